// Round 3
// baseline (4971.952 us; speedup 1.0000x reference)
//
#include <hip/hip_runtime.h>
#include <math.h>

#define BS 256
#define NN 2048
#define KK 64
#define KP1 65
#define NTHREADS 1024
#define NTEAMS 256           // NTHREADS/4 teams; 4 lanes per team
#define ROWS_PT 8            // NN / NTEAMS rows per team
#define MAX_ITER 200
#define SLABR 16             // LDS reduction slab rows

// ---- monotone float<->uint encoding for atomic min/max ----
__device__ __forceinline__ unsigned enc_f32(float f) {
    unsigned b = __float_as_uint(f);
    return b ^ (unsigned)(((int)b >> 31) | (int)0x80000000);
}
__device__ __forceinline__ float dec_f32(unsigned e) {
    unsigned b = (e & 0x80000000u) ? (e & 0x7FFFFFFFu) : ~e;
    return __uint_as_float(b);
}

// ---- kernel 1: global min/max of scores (ignoring -inf for min), count -inf ----
__global__ void minmax_kernel(const float* __restrict__ s,
                              unsigned* __restrict__ maxenc,
                              unsigned* __restrict__ minenc,
                              unsigned* __restrict__ infc) {
    int tid = blockIdx.x * blockDim.x + threadIdx.x;
    int stride = gridDim.x * blockDim.x;
    float mx = -INFINITY, mn = INFINITY;
    unsigned cnt = 0;
    for (int i = tid; i < BS * NN; i += stride) {
        float v = s[i];
        if (isinf(v) && v < 0.0f) cnt++;
        else { mx = fmaxf(mx, v); mn = fminf(mn, v); }
    }
    for (int off = 32; off > 0; off >>= 1) {
        mx = fmaxf(mx, __shfl_down(mx, off));
        mn = fminf(mn, __shfl_down(mn, off));
        cnt += __shfl_down(cnt, off);
    }
    __shared__ float smx[8], smn[8];
    __shared__ unsigned scnt[8];
    int wid = threadIdx.x >> 6, lane = threadIdx.x & 63;
    if (lane == 0) { smx[wid] = mx; smn[wid] = mn; scnt[wid] = cnt; }
    __syncthreads();
    if (threadIdx.x == 0) {
        int nw = blockDim.x >> 6;
        for (int w = 1; w < nw; w++) { mx = fmaxf(mx, smx[w]); mn = fminf(mn, smn[w]); cnt += scnt[w]; }
        atomicMax(maxenc, enc_f32(mx));
        atomicMin(minenc, enc_f32(mn));
        if (cnt) atomicAdd(infc, cnt);
    }
}

// ---- kernel 2: per-batch sort + tau + Gamma0 + 200-iter Sinkhorn + outputs ----
// Factorization: G_ij = exp2(negc2*(s_i-a_j)^2) = p_i * q_j * w_i^(a_j) with
//   w_i = exp2(-2*negc2*s_i), p_i = exp2(negc2*s_i^2), q_j = exp2(negc2*a_j^2).
// Sinkhorn on M_ij = w_i^(64-j) with vt0 = q/65 is exactly equivalent to the
// reference iteration (ut = u*p, vt = q*v for every iterate; Gamma = ut*M*vt).
// Row sums via segmented Horner in w (1 fma/elem); col sums via geometric
// chain (1 mul + 1 fma /elem); col j=64 has M=1.
// ROUND-3 FIX: the compiler pins 1024-thread blocks at 64 VGPRs (launch_bounds
// min-waves arg proven inert in rounds 1-2; spill traffic was +19MB fetch /
// +30MB write). Per-row anchors w, wc = w^(49-16*seg) therefore live in LDS
// (w_sh 8KB + wc_sh 32KB, conflict-free reads: wc addr = tid+const, w addr
// broadcast), shrinking the loop's live set to ~50 floats -> no memory spill.
__global__ void __launch_bounds__(NTHREADS)
sink_main(const float* __restrict__ scores, const float* __restrict__ W,
          float* __restrict__ out,
          const unsigned* __restrict__ maxenc, const unsigned* __restrict__ minenc,
          const unsigned* __restrict__ infc, double* __restrict__ norm_acc)
{
    const int tid  = threadIdx.x;
    const int b    = blockIdx.x;
    const int team = tid >> 2;     // 0..255
    const int seg  = tid & 3;      // 0..3
    const int h16  = team & 15;    // slab row (distinct within each wave)

    __shared__ float ss[NN];                                   // filled scores
    __shared__ float srt[NN];                                  // sort buf; later ut per row
    __shared__ float w_sh[NN];                                 // w per row
    __shared__ float wc_sh[NN * 4] __attribute__((aligned(16))); // wc per (row,seg)
    __shared__ float v_sh[68] __attribute__((aligned(16)));    // vt (65 used)
    __shared__ float vprev_sh[68];                             // vt_{t-1}
    __shared__ float slab[2][SLABR * KP1] __attribute__((aligned(16)));
    __shared__ double red_sh[NTHREADS];
    __shared__ float recS_sh[KK];
    __shared__ float topk_sh[KK];

    const float LOG2E   = 1.4426950408889634f;
    const float inv_n   = 1.0f / 2048.0f;        // exact
    const float nu_last = 1984.0f / 2048.0f;     // exact

    // global scalars
    float smax = dec_f32(*maxenc);
    float smin = dec_f32(*minenc);
    unsigned icnt = *infc;
    float filled = smin - (smax - smin);
    float slo = (icnt > 0) ? filled : smin;
    // C.max() attained at an extreme s with anchor 0 or 64 (convexity)
    float cA = slo * slo, cB = (slo - 64.0f) * (slo - 64.0f);
    float cC = smax * smax, cD = (smax - 64.0f) * (smax - 64.0f);
    float Cmax = fmaxf(fmaxf(cA, cB), fmaxf(cC, cD));
    float negc2 = -(10.0f * LOG2E) / Cmax;       // exp(-C/Cmax/0.1) == exp2(d*d*negc2)
    float m2 = -2.0f * negc2;                    // w = exp2(m2 * s)

    // load + -inf fill
    for (int i = tid; i < NN; i += NTHREADS) {
        float v = scores[(size_t)b * NN + i];
        if (isinf(v) && v < 0.0f) v = filled;
        ss[i] = v; srt[i] = v;
    }
    __syncthreads();

    // bitonic sort (ascending); 1 pair per thread per substep
    for (int size = 2; size <= NN; size <<= 1) {
        for (int stride = size >> 1; stride > 0; stride >>= 1) {
            #pragma unroll
            for (int pp = 0; pp < (NN / 2) / NTHREADS; pp++) {
                int p = tid + pp * NTHREADS;
                int lo = ((p & ~(stride - 1)) << 1) | (p & (stride - 1));
                int hi = lo + stride;
                bool up = ((lo & size) == 0);
                float x = srt[lo], y = srt[hi];
                if ((x > y) == up) { srt[lo] = y; srt[hi] = x; }
            }
            __syncthreads();
        }
    }

    // topk (descending) from sorted
    for (int k = tid; k < KK; k += NTHREADS) topk_sh[k] = srt[NN - 1 - k];

    // tau = sum(sorted * W), fp64 accumulate
    double tp = 0.0;
    for (int i = tid; i < NN; i += NTHREADS) tp += (double)srt[i] * (double)W[i];
    red_sh[tid] = tp;
    __syncthreads();
    for (int s2 = NTHREADS / 2; s2 > 0; s2 >>= 1) {
        if (tid < s2) red_sh[tid] += red_sh[tid + s2];
        __syncthreads();
    }
    float tau = (float)red_sh[0];
    float lt = LOG2E / tau;                      // sigma = 1/(1+exp2(|d|*lt))

    // init vt0 = q/65 (q_j = exp2(negc2*(64-j)^2)); zero both slabs
    if (tid < KP1) {
        float a = (float)(KK - tid);
        v_sh[tid] = __builtin_amdgcn_exp2f(negc2 * a * a) * (1.0f / 65.0f);
    }
    for (int q = tid; q < 2 * SLABR * KP1; q += NTHREADS) ((float*)slab)[q] = 0.0f;

    // per-row anchors into LDS: w and wc[seg] = w^(49-16*seg)
    for (int row = tid; row < NN; row += NTHREADS) {
        float wv = __builtin_amdgcn_exp2f(m2 * ss[row]);
        w_sh[row] = wv;
        float w2 = wv * wv, w4 = w2 * w2, w8 = w4 * w4, w16 = w8 * w8;
        float w17 = wv * w16, w33 = w17 * w16, w49 = w33 * w16;
        ((float4*)wc_sh)[row] = make_float4(w49, w33, w17, wv);
    }
    __syncthreads();

    // ---- Gamma0 column sums S_k into slab[1] (re-zeroed by iter t=0) ----
    {
        float tk[16];
        #pragma unroll
        for (int kk = 0; kk < 16; kk++) tk[kk] = topk_sh[seg * 16 + kk];
        float part[16];
        #pragma unroll
        for (int kk = 0; kk < 16; kk++) part[kk] = 0.0f;
        #pragma unroll 1
        for (int r = 0; r < ROWS_PT; r++) {
            float si = ss[team + NTEAMS * r];
            #pragma unroll
            for (int kk = 0; kk < 16; kk++) {
                float d = fabsf(tk[kk] - si);
                float e = __builtin_amdgcn_exp2f(d * lt);
                part[kk] += 1.0f / (1.0f + e) + 1e-20f;
            }
        }
        #pragma unroll
        for (int kk = 0; kk < 16; kk++)
            atomicAdd(&slab[1][h16 * KP1 + seg * 16 + kk], part[kk]);
    }
    __syncthreads();
    if (tid < KK) {
        float sum = 0.0f;
        #pragma unroll
        for (int g = 0; g < SLABR; g++) sum += slab[1][g * KP1 + tid];
        recS_sh[tid] = 1.0f / sum;
    }
    __syncthreads();

    // ---- Sinkhorn: 200 iterations, Horner row pass + chained col pass ----
    for (int t = 0; t < MAX_ITER; t++) {
        float* sl  = &slab[t & 1][0];
        float* slz = &slab[(t + 1) & 1][0];

        float vloc[16], v64;
        #pragma unroll
        for (int q = 0; q < 4; q++) {
            float4 vv = ((const float4*)(v_sh + seg * 16))[q];
            vloc[4 * q + 0] = vv.x; vloc[4 * q + 1] = vv.y;
            vloc[4 * q + 2] = vv.z; vloc[4 * q + 3] = vv.w;
        }
        v64 = v_sh[64];
        float cp[16];
        #pragma unroll
        for (int j = 0; j < 16; j++) cp[j] = 0.0f;
        float c64 = 0.0f;
        // zero next-iteration slab (readers done before this iter's entry)
        for (int q = tid; q < SLABR * KP1; q += NTHREADS) slz[q] = 0.0f;

        #pragma unroll 2
        for (int pr = 0; pr < ROWS_PT / 2; pr++) {
            const int rowA = team + NTEAMS * (2 * pr);
            const int rowB = rowA + NTEAMS;
            const float wA  = w_sh[rowA];
            const float wB  = w_sh[rowB];
            const float wcA = wc_sh[rowA * 4 + seg];
            const float wcB = wc_sh[rowB * 4 + seg];
            // row sums: Horner in w over this lane's 16 coefficients
            float hA = vloc[0], hB = vloc[0];
            #pragma unroll
            for (int m = 1; m < 16; m++) {
                hA = fmaf(hA, wA, vloc[m]);
                hB = fmaf(hB, wB, vloc[m]);
            }
            float pA = hA * wcA, pB = hB * wcB;
            if (seg == 3) { pA += v64; pB += v64; }   // j=64 term, M=1
            pA += __shfl_xor(pA, 1); pB += __shfl_xor(pB, 1);
            pA += __shfl_xor(pA, 2); pB += __shfl_xor(pB, 2);
            float uA = inv_n / pA;               // IEEE div, matches ref
            float uB = inv_n / pB;
            // col sums: powers ascend as m descends; start = wc = w^(49-16s)
            float gA = wcA, gB = wcB;
            #pragma unroll
            for (int m = 15; m >= 0; m--) {
                cp[m] = fmaf(gA, uA, fmaf(gB, uB, cp[m]));
                gA *= wA; gB *= wB;
            }
            if (seg == 3) c64 += uA + uB;        // col j=64: M=1
        }
        #pragma unroll
        for (int m = 0; m < 16; m++)
            atomicAdd(&sl[h16 * KP1 + seg * 16 + m], cp[m]);
        if (seg == 3) atomicAdd(&sl[h16 * KP1 + 64], c64);
        __syncthreads();
        if (tid < KP1) {
            float cs = 0.0f;
            #pragma unroll
            for (int g = 0; g < SLABR; g++) cs += sl[g * KP1 + tid];
            float nuj = (tid == KK) ? nu_last : inv_n;
            vprev_sh[tid] = v_sh[tid];           // keep vt_{199} for final u
            v_sh[tid] = nuj / cs;
        }
        __syncthreads();
    }

    // ---- final pass A: ut per row (vs v_prev) -> stash in srt (sort buf dead) ----
    {
        float vp[16], vp64;
        #pragma unroll
        for (int j = 0; j < 16; j++) vp[j] = vprev_sh[seg * 16 + j];
        vp64 = vprev_sh[64];
        #pragma unroll
        for (int r = 0; r < ROWS_PT; r++) {
            int row = team + NTEAMS * r;
            float wv = w_sh[row], wcv = wc_sh[row * 4 + seg];
            float h = vp[0];
            #pragma unroll
            for (int m = 1; m < 16; m++) h = fmaf(h, wv, vp[m]);
            float p = h * wcv;
            if (seg == 3) p += vp64;
            p += __shfl_xor(p, 1);
            p += __shfl_xor(p, 2);
            if (seg == 0) srt[row] = inv_n / p;
        }
    }
    __syncthreads();

    // ---- final pass B: outputs + norm (runs once) ----
    {
        float vloc[16], v64;
        #pragma unroll
        for (int j = 0; j < 16; j++) vloc[j] = v_sh[seg * 16 + j];
        v64 = v_sh[64];

        double npart = 0.0;
        #pragma unroll 1
        for (int r = 0; r < ROWS_PT; r++) {
            int row = team + NTEAMS * r;
            float si = ss[row];
            float u  = srt[row];
            float wv = w_sh[row];
            // Gamma row segment: gm[m] = ut * w^(64-16s-m) * vt[m]
            float gm[16];
            float ug = u * wc_sh[row * 4 + seg];
            #pragma unroll
            for (int m = 15; m >= 0; m--) { gm[m] = ug * vloc[m]; ug *= wv; }

            float g0sum = 0.0f;
            float* orow = out + ((size_t)b * NN + row) * KK + seg * 16;
            #pragma unroll
            for (int q = 0; q < 4; q++) {
                float4 o;
                #define DO_K(kk_, fld) { const int kl = 4 * q + kk_;            \
                    float dd = fabsf(topk_sh[seg * 16 + kl] - si);              \
                    float e  = __builtin_amdgcn_exp2f(dd * lt);                 \
                    float sg = 1.0f / (1.0f + e) + 1e-20f;                      \
                    float g0 = (sg * recS_sh[seg * 16 + kl]) * inv_n;           \
                    g0sum += g0;                                                \
                    float df = gm[kl] - g0; npart += (double)df * (double)df;   \
                    o.fld = gm[kl] * 2048.0f; }
                DO_K(0, x) DO_K(1, y) DO_K(2, z) DO_K(3, w)
                #undef DO_K
                ((float4*)orow)[q] = o;
            }
            float gtot = g0sum;
            gtot += __shfl_xor(gtot, 1);
            gtot += __shfl_xor(gtot, 2);
            if (seg == 3) {
                float last = inv_n - gtot;
                last = fminf(fmaxf(last, 1e-20f), 1.0f - 1e-20f);   // clip
                float gm64 = u * v64;            // M_{i,64} = w^0 = 1
                float df = gm64 - last;
                npart += (double)df * (double)df;
            }
        }

        __syncthreads();
        red_sh[tid] = npart;
        __syncthreads();
        for (int s2 = NTHREADS / 2; s2 > 0; s2 >>= 1) {
            if (tid < s2) red_sh[tid] += red_sh[tid + s2];
            __syncthreads();
        }
        if (tid == 0) atomicAdd(norm_acc, red_sh[0]);
    }
}

// ---- kernel 3: finalize norm ----
__global__ void finalize_kernel(const double* __restrict__ norm_acc, float* __restrict__ out) {
    if (threadIdx.x == 0 && blockIdx.x == 0)
        out[(size_t)BS * NN * KK] = (float)sqrt(*norm_acc);
}

extern "C" void kernel_launch(void* const* d_in, const int* in_sizes, int n_in,
                              void* d_out, int out_size, void* d_ws, size_t ws_size,
                              hipStream_t stream) {
    const float* scores = (const float*)d_in[0];
    const float* W = (const float*)d_in[1];
    float* out = (float*)d_out;

    // ws layout: [0..3] max_enc(0), [4..7] inf_count(0),
    //            [8..15] norm_acc double(0), [16..19] min_enc(0xFFFFFFFF)
    unsigned* maxenc = (unsigned*)d_ws;
    unsigned* infc   = maxenc + 1;
    double*  nacc    = (double*)((char*)d_ws + 8);
    unsigned* minenc = (unsigned*)((char*)d_ws + 16);

    hipMemsetAsync(d_ws, 0, 16, stream);
    hipMemsetAsync((char*)d_ws + 16, 0xFF, 4, stream);

    hipLaunchKernelGGL(minmax_kernel, dim3(256), dim3(256), 0, stream,
                       scores, maxenc, minenc, infc);
    hipLaunchKernelGGL(sink_main, dim3(BS), dim3(NTHREADS), 0, stream,
                       scores, W, out, maxenc, minenc, infc, nacc);
    hipLaunchKernelGGL(finalize_kernel, dim3(1), dim3(64), 0, stream, nacc, out);
}

// Round 4
// 1355.766 us; speedup vs baseline: 3.6673x; 3.6673x over previous
//
#include <hip/hip_runtime.h>
#include <math.h>

#define BS 256
#define NN 2048
#define KK 64
#define KP1 65
#define NTHREADS 1024
#define NTEAMS 256           // NTHREADS/4 teams; 4 lanes per team
#define ROWS_PT 8            // NN / NTEAMS rows per team
#define MAX_ITER 200
#define SLABR 16             // one slab row per wave (16 waves)

// ---- monotone float<->uint encoding for atomic min/max ----
__device__ __forceinline__ unsigned enc_f32(float f) {
    unsigned b = __float_as_uint(f);
    return b ^ (unsigned)(((int)b >> 31) | (int)0x80000000);
}
__device__ __forceinline__ float dec_f32(unsigned e) {
    unsigned b = (e & 0x80000000u) ? (e & 0x7FFFFFFFu) : ~e;
    return __uint_as_float(b);
}

// ---- kernel 1: global min/max of scores (ignoring -inf for min), count -inf ----
__global__ void minmax_kernel(const float* __restrict__ s,
                              unsigned* __restrict__ maxenc,
                              unsigned* __restrict__ minenc,
                              unsigned* __restrict__ infc) {
    int tid = blockIdx.x * blockDim.x + threadIdx.x;
    int stride = gridDim.x * blockDim.x;
    float mx = -INFINITY, mn = INFINITY;
    unsigned cnt = 0;
    for (int i = tid; i < BS * NN; i += stride) {
        float v = s[i];
        if (isinf(v) && v < 0.0f) cnt++;
        else { mx = fmaxf(mx, v); mn = fminf(mn, v); }
    }
    for (int off = 32; off > 0; off >>= 1) {
        mx = fmaxf(mx, __shfl_down(mx, off));
        mn = fminf(mn, __shfl_down(mn, off));
        cnt += __shfl_down(cnt, off);
    }
    __shared__ float smx[8], smn[8];
    __shared__ unsigned scnt[8];
    int wid = threadIdx.x >> 6, lane = threadIdx.x & 63;
    if (lane == 0) { smx[wid] = mx; smn[wid] = mn; scnt[wid] = cnt; }
    __syncthreads();
    if (threadIdx.x == 0) {
        int nw = blockDim.x >> 6;
        for (int w = 1; w < nw; w++) { mx = fmaxf(mx, smx[w]); mn = fminf(mn, smn[w]); cnt += scnt[w]; }
        atomicMax(maxenc, enc_f32(mx));
        atomicMin(minenc, enc_f32(mn));
        if (cnt) atomicAdd(infc, cnt);
    }
}

// ---- kernel 2: per-batch sort + tau + Gamma0 + 200-iter Sinkhorn + outputs ----
// Factorization: G_ij = exp2(negc2*(s_i-a_j)^2) = p_i * q_j * w_i^(a_j) with
//   w_i = exp2(-2*negc2*s_i).  Sinkhorn on M_ij = w_i^(64-j) with vt0 = q/65
// is exactly equivalent to the reference iteration (ut=u*p, vt=q*v; Gamma
// unchanged).  Row sums: segmented Horner in w; col sums: geometric chain.
// ROUND-4 FIX: rounds 0-3 were DS-pipe-bound on the slab atomicAdd reduction
// (all 16 waves RMW the SAME 16x65 region -> 16-way same-address serial
// contention; stall scaled with wave count: 28.6K cy/iter @8 waves, 51.5K
// @16).  Replaced by in-wave butterfly (__shfl_xor 4/8/16/32 over the team
// bits) + plain ds_write_b128 from lanes 0-3 into a PER-WAVE slab row ->
// zero contention, and the slab zero/double-buffer loop is deleted (writers
// fully overwrite their row each iter).
__global__ void __launch_bounds__(NTHREADS)
sink_main(const float* __restrict__ scores, const float* __restrict__ W,
          float* __restrict__ out,
          const unsigned* __restrict__ maxenc, const unsigned* __restrict__ minenc,
          const unsigned* __restrict__ infc, double* __restrict__ norm_acc)
{
    const int tid  = threadIdx.x;
    const int b    = blockIdx.x;
    const int team = tid >> 2;     // 0..255
    const int seg  = tid & 3;      // 0..3
    const int wid  = tid >> 6;     // wave id 0..15
    const int lane = tid & 63;

    __shared__ float ss[NN];                                   // filled scores
    __shared__ float srt[NN];                                  // sort buf; later ut per row
    __shared__ float w_sh[NN];                                 // w per row
    __shared__ float wc_sh[NN * 4] __attribute__((aligned(16))); // wc per (row,seg)
    __shared__ float v_sh[68] __attribute__((aligned(16)));    // vt (65 used)
    __shared__ float vprev_sh[68];                             // vt_{t-1}
    __shared__ float slab[SLABR * KP1] __attribute__((aligned(16))); // per-wave partials
    __shared__ double red_sh[NTHREADS];
    __shared__ float recS_sh[KK];
    __shared__ float topk_sh[KK];

    const float LOG2E   = 1.4426950408889634f;
    const float inv_n   = 1.0f / 2048.0f;        // exact
    const float nu_last = 1984.0f / 2048.0f;     // exact

    // global scalars
    float smax = dec_f32(*maxenc);
    float smin = dec_f32(*minenc);
    unsigned icnt = *infc;
    float filled = smin - (smax - smin);
    float slo = (icnt > 0) ? filled : smin;
    // C.max() attained at an extreme s with anchor 0 or 64 (convexity)
    float cA = slo * slo, cB = (slo - 64.0f) * (slo - 64.0f);
    float cC = smax * smax, cD = (smax - 64.0f) * (smax - 64.0f);
    float Cmax = fmaxf(fmaxf(cA, cB), fmaxf(cC, cD));
    float negc2 = -(10.0f * LOG2E) / Cmax;       // exp(-C/Cmax/0.1) == exp2(d*d*negc2)
    float m2 = -2.0f * negc2;                    // w = exp2(m2 * s)

    // load + -inf fill
    for (int i = tid; i < NN; i += NTHREADS) {
        float v = scores[(size_t)b * NN + i];
        if (isinf(v) && v < 0.0f) v = filled;
        ss[i] = v; srt[i] = v;
    }
    __syncthreads();

    // bitonic sort (ascending); 1 pair per thread per substep
    for (int size = 2; size <= NN; size <<= 1) {
        for (int stride = size >> 1; stride > 0; stride >>= 1) {
            #pragma unroll
            for (int pp = 0; pp < (NN / 2) / NTHREADS; pp++) {
                int p = tid + pp * NTHREADS;
                int lo = ((p & ~(stride - 1)) << 1) | (p & (stride - 1));
                int hi = lo + stride;
                bool up = ((lo & size) == 0);
                float x = srt[lo], y = srt[hi];
                if ((x > y) == up) { srt[lo] = y; srt[hi] = x; }
            }
            __syncthreads();
        }
    }

    // topk (descending) from sorted
    for (int k = tid; k < KK; k += NTHREADS) topk_sh[k] = srt[NN - 1 - k];

    // tau = sum(sorted * W), fp64 accumulate
    double tp = 0.0;
    for (int i = tid; i < NN; i += NTHREADS) tp += (double)srt[i] * (double)W[i];
    red_sh[tid] = tp;
    __syncthreads();
    for (int s2 = NTHREADS / 2; s2 > 0; s2 >>= 1) {
        if (tid < s2) red_sh[tid] += red_sh[tid + s2];
        __syncthreads();
    }
    float tau = (float)red_sh[0];
    float lt = LOG2E / tau;                      // sigma = 1/(1+exp2(|d|*lt))

    // init vt0 = q/65 (q_j = exp2(negc2*(64-j)^2))
    if (tid < KP1) {
        float a = (float)(KK - tid);
        v_sh[tid] = __builtin_amdgcn_exp2f(negc2 * a * a) * (1.0f / 65.0f);
    }

    // per-row anchors into LDS: w and wc[seg] = w^(49-16*seg)
    for (int row = tid; row < NN; row += NTHREADS) {
        float wv = __builtin_amdgcn_exp2f(m2 * ss[row]);
        w_sh[row] = wv;
        float w2 = wv * wv, w4 = w2 * w2, w8 = w4 * w4, w16 = w8 * w8;
        float w17 = wv * w16, w33 = w17 * w16, w49 = w33 * w16;
        ((float4*)wc_sh)[row] = make_float4(w49, w33, w17, wv);
    }
    __syncthreads();

    const bool writer = ((lane >> 2) == 0);      // lanes 0..3: one per seg

    // ---- Gamma0 column sums S_k: butterfly + per-wave slab row ----
    {
        float tk[16];
        #pragma unroll
        for (int kk = 0; kk < 16; kk++) tk[kk] = topk_sh[seg * 16 + kk];
        float part[16];
        #pragma unroll
        for (int kk = 0; kk < 16; kk++) part[kk] = 0.0f;
        #pragma unroll 1
        for (int r = 0; r < ROWS_PT; r++) {
            float si = ss[team + NTEAMS * r];
            #pragma unroll
            for (int kk = 0; kk < 16; kk++) {
                float d = fabsf(tk[kk] - si);
                float e = __builtin_amdgcn_exp2f(d * lt);
                part[kk] += 1.0f / (1.0f + e) + 1e-20f;
            }
        }
        #pragma unroll
        for (int kk = 0; kk < 16; kk++) {
            part[kk] += __shfl_xor(part[kk], 4);
            part[kk] += __shfl_xor(part[kk], 8);
            part[kk] += __shfl_xor(part[kk], 16);
            part[kk] += __shfl_xor(part[kk], 32);
        }
        if (writer) {
            float4* dst = (float4*)&slab[wid * KP1 + seg * 16];
            dst[0] = make_float4(part[0], part[1], part[2], part[3]);
            dst[1] = make_float4(part[4], part[5], part[6], part[7]);
            dst[2] = make_float4(part[8], part[9], part[10], part[11]);
            dst[3] = make_float4(part[12], part[13], part[14], part[15]);
        }
    }
    __syncthreads();
    if (tid < KK) {
        float sum = 0.0f;
        #pragma unroll
        for (int g = 0; g < SLABR; g++) sum += slab[g * KP1 + tid];
        recS_sh[tid] = 1.0f / sum;
    }
    __syncthreads();

    // ---- Sinkhorn: 200 iterations, Horner row pass + chained col pass ----
    for (int t = 0; t < MAX_ITER; t++) {
        float vloc[16], v64;
        #pragma unroll
        for (int q = 0; q < 4; q++) {
            float4 vv = ((const float4*)(v_sh + seg * 16))[q];
            vloc[4 * q + 0] = vv.x; vloc[4 * q + 1] = vv.y;
            vloc[4 * q + 2] = vv.z; vloc[4 * q + 3] = vv.w;
        }
        v64 = v_sh[64];
        float cp[16];
        #pragma unroll
        for (int j = 0; j < 16; j++) cp[j] = 0.0f;
        float c64 = 0.0f;

        #pragma unroll 2
        for (int pr = 0; pr < ROWS_PT / 2; pr++) {
            const int rowA = team + NTEAMS * (2 * pr);
            const int rowB = rowA + NTEAMS;
            const float wA  = w_sh[rowA];
            const float wB  = w_sh[rowB];
            const float wcA = wc_sh[rowA * 4 + seg];
            const float wcB = wc_sh[rowB * 4 + seg];
            // row sums: Horner in w over this lane's 16 coefficients
            float hA = vloc[0], hB = vloc[0];
            #pragma unroll
            for (int m = 1; m < 16; m++) {
                hA = fmaf(hA, wA, vloc[m]);
                hB = fmaf(hB, wB, vloc[m]);
            }
            float pA = hA * wcA, pB = hB * wcB;
            if (seg == 3) { pA += v64; pB += v64; }   // j=64 term, M=1
            pA += __shfl_xor(pA, 1); pB += __shfl_xor(pB, 1);
            pA += __shfl_xor(pA, 2); pB += __shfl_xor(pB, 2);
            float uA = inv_n / pA;               // IEEE div, matches ref
            float uB = inv_n / pB;
            // col sums: powers ascend as m descends; start = wc = w^(49-16s)
            float gA = wcA, gB = wcB;
            #pragma unroll
            for (int m = 15; m >= 0; m--) {
                cp[m] = fmaf(gA, uA, fmaf(gB, uB, cp[m]));
                gA *= wA; gB *= wB;
            }
            if (seg == 3) c64 += uA + uB;        // col j=64: M=1
        }

        // in-wave butterfly over team bits (lane bits 2..5): 16 teams -> sum
        #pragma unroll
        for (int m = 0; m < 16; m++) {
            cp[m] += __shfl_xor(cp[m], 4);
            cp[m] += __shfl_xor(cp[m], 8);
            cp[m] += __shfl_xor(cp[m], 16);
            cp[m] += __shfl_xor(cp[m], 32);
        }
        c64 += __shfl_xor(c64, 4);
        c64 += __shfl_xor(c64, 8);
        c64 += __shfl_xor(c64, 16);
        c64 += __shfl_xor(c64, 32);
        if (writer) {
            float4* dst = (float4*)&slab[wid * KP1 + seg * 16];
            dst[0] = make_float4(cp[0], cp[1], cp[2], cp[3]);
            dst[1] = make_float4(cp[4], cp[5], cp[6], cp[7]);
            dst[2] = make_float4(cp[8], cp[9], cp[10], cp[11]);
            dst[3] = make_float4(cp[12], cp[13], cp[14], cp[15]);
            if (seg == 3) slab[wid * KP1 + 64] = c64;
        }
        __syncthreads();
        if (tid < KP1) {
            float cs = 0.0f;
            #pragma unroll
            for (int g = 0; g < SLABR; g++) cs += slab[g * KP1 + tid];
            float nuj = (tid == KK) ? nu_last : inv_n;
            vprev_sh[tid] = v_sh[tid];           // keep vt_{199} for final u
            v_sh[tid] = nuj / cs;
        }
        __syncthreads();
    }

    // ---- final pass A: ut per row (vs v_prev) -> stash in srt (sort buf dead) ----
    {
        float vp[16], vp64;
        #pragma unroll
        for (int j = 0; j < 16; j++) vp[j] = vprev_sh[seg * 16 + j];
        vp64 = vprev_sh[64];
        #pragma unroll
        for (int r = 0; r < ROWS_PT; r++) {
            int row = team + NTEAMS * r;
            float wv = w_sh[row], wcv = wc_sh[row * 4 + seg];
            float h = vp[0];
            #pragma unroll
            for (int m = 1; m < 16; m++) h = fmaf(h, wv, vp[m]);
            float p = h * wcv;
            if (seg == 3) p += vp64;
            p += __shfl_xor(p, 1);
            p += __shfl_xor(p, 2);
            if (seg == 0) srt[row] = inv_n / p;
        }
    }
    __syncthreads();

    // ---- final pass B: outputs + norm (runs once) ----
    {
        float vloc[16], v64;
        #pragma unroll
        for (int j = 0; j < 16; j++) vloc[j] = v_sh[seg * 16 + j];
        v64 = v_sh[64];

        double npart = 0.0;
        #pragma unroll 1
        for (int r = 0; r < ROWS_PT; r++) {
            int row = team + NTEAMS * r;
            float si = ss[row];
            float u  = srt[row];
            float wv = w_sh[row];
            // Gamma row segment: gm[m] = ut * w^(64-16s-m) * vt[m]
            float gm[16];
            float ug = u * wc_sh[row * 4 + seg];
            #pragma unroll
            for (int m = 15; m >= 0; m--) { gm[m] = ug * vloc[m]; ug *= wv; }

            float g0sum = 0.0f;
            float* orow = out + ((size_t)b * NN + row) * KK + seg * 16;
            #pragma unroll
            for (int q = 0; q < 4; q++) {
                float4 o;
                #define DO_K(kk_, fld) { const int kl = 4 * q + kk_;            \
                    float dd = fabsf(topk_sh[seg * 16 + kl] - si);              \
                    float e  = __builtin_amdgcn_exp2f(dd * lt);                 \
                    float sg = 1.0f / (1.0f + e) + 1e-20f;                      \
                    float g0 = (sg * recS_sh[seg * 16 + kl]) * inv_n;           \
                    g0sum += g0;                                                \
                    float df = gm[kl] - g0; npart += (double)df * (double)df;   \
                    o.fld = gm[kl] * 2048.0f; }
                DO_K(0, x) DO_K(1, y) DO_K(2, z) DO_K(3, w)
                #undef DO_K
                ((float4*)orow)[q] = o;
            }
            float gtot = g0sum;
            gtot += __shfl_xor(gtot, 1);
            gtot += __shfl_xor(gtot, 2);
            if (seg == 3) {
                float last = inv_n - gtot;
                last = fminf(fmaxf(last, 1e-20f), 1.0f - 1e-20f);   // clip
                float gm64 = u * v64;            // M_{i,64} = w^0 = 1
                float df = gm64 - last;
                npart += (double)df * (double)df;
            }
        }

        __syncthreads();
        red_sh[tid] = npart;
        __syncthreads();
        for (int s2 = NTHREADS / 2; s2 > 0; s2 >>= 1) {
            if (tid < s2) red_sh[tid] += red_sh[tid + s2];
            __syncthreads();
        }
        if (tid == 0) atomicAdd(norm_acc, red_sh[0]);
    }
}

// ---- kernel 3: finalize norm ----
__global__ void finalize_kernel(const double* __restrict__ norm_acc, float* __restrict__ out) {
    if (threadIdx.x == 0 && blockIdx.x == 0)
        out[(size_t)BS * NN * KK] = (float)sqrt(*norm_acc);
}

extern "C" void kernel_launch(void* const* d_in, const int* in_sizes, int n_in,
                              void* d_out, int out_size, void* d_ws, size_t ws_size,
                              hipStream_t stream) {
    const float* scores = (const float*)d_in[0];
    const float* W = (const float*)d_in[1];
    float* out = (float*)d_out;

    // ws layout: [0..3] max_enc(0), [4..7] inf_count(0),
    //            [8..15] norm_acc double(0), [16..19] min_enc(0xFFFFFFFF)
    unsigned* maxenc = (unsigned*)d_ws;
    unsigned* infc   = maxenc + 1;
    double*  nacc    = (double*)((char*)d_ws + 8);
    unsigned* minenc = (unsigned*)((char*)d_ws + 16);

    hipMemsetAsync(d_ws, 0, 16, stream);
    hipMemsetAsync((char*)d_ws + 16, 0xFF, 4, stream);

    hipLaunchKernelGGL(minmax_kernel, dim3(256), dim3(256), 0, stream,
                       scores, maxenc, minenc, infc);
    hipLaunchKernelGGL(sink_main, dim3(BS), dim3(NTHREADS), 0, stream,
                       scores, W, out, maxenc, minenc, infc, nacc);
    hipLaunchKernelGGL(finalize_kernel, dim3(1), dim3(64), 0, stream, nacc, out);
}

// Round 5
// 999.749 us; speedup vs baseline: 4.9732x; 1.3561x over previous
//
#include <hip/hip_runtime.h>
#include <math.h>

#define BS 256
#define NN 2048
#define KK 64
#define KP1 65
#define NTHREADS 1024
#define NTEAMS 256           // NTHREADS/4 teams; 4 lanes per team
#define ROWS_PT 8            // NN / NTEAMS rows per team
#define NPAIRS 4             // ROWS_PT/2 row-pairs per team
#define MAX_ITER 200
#define SLABR 32             // two slab rows per wave (one per 32-lane half)
#define SLABS 68             // slab row stride (floats): 16B-aligned rows

// cross-lane helpers that stay OFF the DS-bpermute path:
//   quad_perm xor1=0xB1, xor2=0x4E (VALU DPP); row_ror:8 = 0x128 == lane^8
//   within a 16-lane row (VALU DPP); ds_swizzle xor4=0x101F, xor16=0x401F
//   (DS, but 1 op, no address VGPR, conflict-free permutation).
#define DPP_ADD(x, ctrl) ((x) + __int_as_float(__builtin_amdgcn_mov_dpp(      \
                              __float_as_int(x), (ctrl), 0xF, 0xF, true)))
#define SWZ_ADD(x, pat)  ((x) + __int_as_float(__builtin_amdgcn_ds_swizzle(   \
                              __float_as_int(x), (pat))))

// ---- monotone float<->uint encoding for atomic min/max ----
__device__ __forceinline__ unsigned enc_f32(float f) {
    unsigned b = __float_as_uint(f);
    return b ^ (unsigned)(((int)b >> 31) | (int)0x80000000);
}
__device__ __forceinline__ float dec_f32(unsigned e) {
    unsigned b = (e & 0x80000000u) ? (e & 0x7FFFFFFFu) : ~e;
    return __uint_as_float(b);
}

// ---- kernel 1: global min/max of scores (ignoring -inf for min), count -inf ----
__global__ void minmax_kernel(const float* __restrict__ s,
                              unsigned* __restrict__ maxenc,
                              unsigned* __restrict__ minenc,
                              unsigned* __restrict__ infc) {
    int tid = blockIdx.x * blockDim.x + threadIdx.x;
    int stride = gridDim.x * blockDim.x;
    float mx = -INFINITY, mn = INFINITY;
    unsigned cnt = 0;
    for (int i = tid; i < BS * NN; i += stride) {
        float v = s[i];
        if (isinf(v) && v < 0.0f) cnt++;
        else { mx = fmaxf(mx, v); mn = fminf(mn, v); }
    }
    for (int off = 32; off > 0; off >>= 1) {
        mx = fmaxf(mx, __shfl_down(mx, off));
        mn = fminf(mn, __shfl_down(mn, off));
        cnt += __shfl_down(cnt, off);
    }
    __shared__ float smx[8], smn[8];
    __shared__ unsigned scnt[8];
    int wid = threadIdx.x >> 6, lane = threadIdx.x & 63;
    if (lane == 0) { smx[wid] = mx; smn[wid] = mn; scnt[wid] = cnt; }
    __syncthreads();
    if (threadIdx.x == 0) {
        int nw = blockDim.x >> 6;
        for (int w = 1; w < nw; w++) { mx = fmaxf(mx, smx[w]); mn = fminf(mn, smn[w]); cnt += scnt[w]; }
        atomicMax(maxenc, enc_f32(mx));
        atomicMin(minenc, enc_f32(mn));
        if (cnt) atomicAdd(infc, cnt);
    }
}

// ---- kernel 2: per-batch sort + tau + Gamma0 + 200-iter Sinkhorn + outputs ----
// Factorization: Sinkhorn on M_ij = w_i^(64-j), w_i = exp2(-2*negc2*s_i), with
// vt0 = q/65 is exactly equivalent to the reference (ut=u*p, vt=q*v).
// Row sums: segmented Horner in w; col sums: geometric chain.
// ROUND-5 FIX: round 4 was DS-pipe-bound on __shfl_xor (= ds_bpermute + addr
// VGPR; ~84/thread/iter).  All cross-lane ops now use DPP quad_perm (xor1/2),
// DPP row_ror:8 (xor8) and ds_swizzle (xor4/16); the xor32 step is dropped in
// favor of per-HALF-wave slab rows (32 rows).  w/wc reads fused into one
// ds_read_b128 per row-pair via the pairs_sh table (precomputed once; kept in
// LDS deliberately -- hoisting 16 floats to registers spilled in rounds 1-3
// at the 64-VGPR cap).
__global__ void __launch_bounds__(NTHREADS)
sink_main(const float* __restrict__ scores, const float* __restrict__ W,
          float* __restrict__ out,
          const unsigned* __restrict__ maxenc, const unsigned* __restrict__ minenc,
          const unsigned* __restrict__ infc, double* __restrict__ norm_acc)
{
    const int tid  = threadIdx.x;
    const int b    = blockIdx.x;
    const int team = tid >> 2;     // 0..255
    const int seg  = tid & 3;      // 0..3
    const int wid  = tid >> 6;     // wave id 0..15
    const int lane = tid & 63;

    __shared__ float ss[NN];                                   // filled scores
    __shared__ float srt[NN];                                  // sort buf; later ut per row
    __shared__ float4 pairs_sh[NPAIRS * NTEAMS * 4];           // (wcA,wA,wcB,wB) per (pr,team,seg)
    __shared__ float v_sh[68] __attribute__((aligned(16)));    // vt (65 used)
    __shared__ float vprev_sh[68];                             // vt_{t-1}
    __shared__ float slab[SLABR * SLABS] __attribute__((aligned(16))); // per-half-wave partials
    __shared__ double red_sh[NTHREADS];
    __shared__ float recS_sh[KK];
    __shared__ float topk_sh[KK];

    const float LOG2E   = 1.4426950408889634f;
    const float inv_n   = 1.0f / 2048.0f;        // exact
    const float nu_last = 1984.0f / 2048.0f;     // exact

    // global scalars
    float smax = dec_f32(*maxenc);
    float smin = dec_f32(*minenc);
    unsigned icnt = *infc;
    float filled = smin - (smax - smin);
    float slo = (icnt > 0) ? filled : smin;
    // C.max() attained at an extreme s with anchor 0 or 64 (convexity)
    float cA = slo * slo, cB = (slo - 64.0f) * (slo - 64.0f);
    float cC = smax * smax, cD = (smax - 64.0f) * (smax - 64.0f);
    float Cmax = fmaxf(fmaxf(cA, cB), fmaxf(cC, cD));
    float negc2 = -(10.0f * LOG2E) / Cmax;       // exp(-C/Cmax/0.1) == exp2(d*d*negc2)
    float m2 = -2.0f * negc2;                    // w = exp2(m2 * s)

    // load + -inf fill
    for (int i = tid; i < NN; i += NTHREADS) {
        float v = scores[(size_t)b * NN + i];
        if (isinf(v) && v < 0.0f) v = filled;
        ss[i] = v; srt[i] = v;
    }
    __syncthreads();

    // bitonic sort (ascending); 1 pair per thread per substep
    for (int size = 2; size <= NN; size <<= 1) {
        for (int stride = size >> 1; stride > 0; stride >>= 1) {
            #pragma unroll
            for (int pp = 0; pp < (NN / 2) / NTHREADS; pp++) {
                int p = tid + pp * NTHREADS;
                int lo = ((p & ~(stride - 1)) << 1) | (p & (stride - 1));
                int hi = lo + stride;
                bool up = ((lo & size) == 0);
                float x = srt[lo], y = srt[hi];
                if ((x > y) == up) { srt[lo] = y; srt[hi] = x; }
            }
            __syncthreads();
        }
    }

    // topk (descending) from sorted
    for (int k = tid; k < KK; k += NTHREADS) topk_sh[k] = srt[NN - 1 - k];

    // tau = sum(sorted * W), fp64 accumulate
    double tp = 0.0;
    for (int i = tid; i < NN; i += NTHREADS) tp += (double)srt[i] * (double)W[i];
    red_sh[tid] = tp;
    __syncthreads();
    for (int s2 = NTHREADS / 2; s2 > 0; s2 >>= 1) {
        if (tid < s2) red_sh[tid] += red_sh[tid + s2];
        __syncthreads();
    }
    float tau = (float)red_sh[0];
    float lt = LOG2E / tau;                      // sigma = 1/(1+exp2(|d|*lt))

    // init vt0 = q/65 (q_j = exp2(negc2*(64-j)^2))
    if (tid < KP1) {
        float a = (float)(KK - tid);
        v_sh[tid] = __builtin_amdgcn_exp2f(negc2 * a * a) * (1.0f / 65.0f);
    }

    // pairs table: (wcA, wA, wcB, wB) per (pr, team, seg); wc = w^(49-16*seg)
    for (int item = tid; item < NPAIRS * NTEAMS * 4; item += NTHREADS) {
        int pr = item >> 10;                 // NTEAMS*4 = 1024
        int tm = (item >> 2) & (NTEAMS - 1);
        int sg = item & 3;
        int rowA = tm + NTEAMS * (2 * pr);
        int rowB = rowA + NTEAMS;
        float wA = __builtin_amdgcn_exp2f(m2 * ss[rowA]);
        float wB = __builtin_amdgcn_exp2f(m2 * ss[rowB]);
        float a2 = wA * wA, a4 = a2 * a2, a8 = a4 * a4, a16 = a8 * a8;
        float b2 = wB * wB, b4 = b2 * b2, b8 = b4 * b4, b16 = b8 * b8;
        float wcA = wA, wcB = wB;            // sg==3: w^1
        if (sg < 3) { wcA *= a16; wcB *= b16; }   // sg==2: w^17
        if (sg < 2) { wcA *= a16; wcB *= b16; }   // sg==1: w^33
        if (sg < 1) { wcA *= a16; wcB *= b16; }   // sg==0: w^49
        pairs_sh[item] = make_float4(wcA, wA, wcB, wB);
    }
    __syncthreads();

    const bool writer = ((lane & 0x1C) == 0);    // lanes 0-3 and 32-35
    const int  half   = lane >> 5;               // which 32-lane half
    const int  srow   = wid * 2 + half;          // this half's slab row

    // ---- Gamma0 column sums S_k: butterfly (xor4/8/16) + per-half slab row ----
    {
        float tk[16];
        #pragma unroll
        for (int kk = 0; kk < 16; kk++) tk[kk] = topk_sh[seg * 16 + kk];
        float part[16];
        #pragma unroll
        for (int kk = 0; kk < 16; kk++) part[kk] = 0.0f;
        #pragma unroll 1
        for (int r = 0; r < ROWS_PT; r++) {
            float si = ss[team + NTEAMS * r];
            #pragma unroll
            for (int kk = 0; kk < 16; kk++) {
                float d = fabsf(tk[kk] - si);
                float e = __builtin_amdgcn_exp2f(d * lt);
                part[kk] += 1.0f / (1.0f + e) + 1e-20f;
            }
        }
        #pragma unroll
        for (int kk = 0; kk < 16; kk++) {
            part[kk] = SWZ_ADD(part[kk], 0x101F);   // xor4
            part[kk] = DPP_ADD(part[kk], 0x128);    // xor8 (row_ror:8)
            part[kk] = SWZ_ADD(part[kk], 0x401F);   // xor16
        }
        if (writer) {
            float4* dst = (float4*)&slab[srow * SLABS + seg * 16];
            dst[0] = make_float4(part[0], part[1], part[2], part[3]);
            dst[1] = make_float4(part[4], part[5], part[6], part[7]);
            dst[2] = make_float4(part[8], part[9], part[10], part[11]);
            dst[3] = make_float4(part[12], part[13], part[14], part[15]);
        }
    }
    __syncthreads();
    if (tid < KK) {
        float sum = 0.0f;
        #pragma unroll
        for (int g = 0; g < SLABR; g++) sum += slab[g * SLABS + tid];
        recS_sh[tid] = 1.0f / sum;
    }
    __syncthreads();

    // ---- Sinkhorn: 200 iterations, Horner row pass + chained col pass ----
    for (int t = 0; t < MAX_ITER; t++) {
        float vloc[16], v64;
        #pragma unroll
        for (int q = 0; q < 4; q++) {
            float4 vv = ((const float4*)(v_sh + seg * 16))[q];
            vloc[4 * q + 0] = vv.x; vloc[4 * q + 1] = vv.y;
            vloc[4 * q + 2] = vv.z; vloc[4 * q + 3] = vv.w;
        }
        v64 = v_sh[64];
        float cp[16];
        #pragma unroll
        for (int j = 0; j < 16; j++) cp[j] = 0.0f;
        float c64 = 0.0f;

        #pragma unroll 2
        for (int pr = 0; pr < NPAIRS; pr++) {
            const float4 pw = pairs_sh[pr * (NTEAMS * 4) + team * 4 + seg];
            const float wcA = pw.x, wA = pw.y, wcB = pw.z, wB = pw.w;
            // row sums: Horner in w over this lane's 16 coefficients
            float hA = vloc[0], hB = vloc[0];
            #pragma unroll
            for (int m = 1; m < 16; m++) {
                hA = fmaf(hA, wA, vloc[m]);
                hB = fmaf(hB, wB, vloc[m]);
            }
            float pA = hA * wcA, pB = hB * wcB;
            if (seg == 3) { pA += v64; pB += v64; }   // j=64 term, M=1
            pA = DPP_ADD(pA, 0xB1);                   // xor1 (quad_perm)
            pB = DPP_ADD(pB, 0xB1);
            pA = DPP_ADD(pA, 0x4E);                   // xor2 (quad_perm)
            pB = DPP_ADD(pB, 0x4E);
            float uA = inv_n / pA;               // IEEE div, matches ref
            float uB = inv_n / pB;
            // col sums: powers ascend as m descends; start = wc = w^(49-16s)
            float gA = wcA, gB = wcB;
            #pragma unroll
            for (int m = 15; m >= 0; m--) {
                cp[m] = fmaf(gA, uA, fmaf(gB, uB, cp[m]));
                gA *= wA; gB *= wB;
            }
            if (seg == 3) c64 += uA + uB;        // col j=64: M=1
        }

        // cross-team reduce within each 32-lane half (team bits 2..4)
        #pragma unroll
        for (int m = 0; m < 16; m++) {
            cp[m] = SWZ_ADD(cp[m], 0x101F);      // xor4
            cp[m] = DPP_ADD(cp[m], 0x128);       // xor8
            cp[m] = SWZ_ADD(cp[m], 0x401F);      // xor16
        }
        c64 = SWZ_ADD(c64, 0x101F);
        c64 = DPP_ADD(c64, 0x128);
        c64 = SWZ_ADD(c64, 0x401F);
        if (writer) {
            float4* dst = (float4*)&slab[srow * SLABS + seg * 16];
            dst[0] = make_float4(cp[0], cp[1], cp[2], cp[3]);
            dst[1] = make_float4(cp[4], cp[5], cp[6], cp[7]);
            dst[2] = make_float4(cp[8], cp[9], cp[10], cp[11]);
            dst[3] = make_float4(cp[12], cp[13], cp[14], cp[15]);
            if (seg == 3) slab[srow * SLABS + 64] = c64;
        }
        __syncthreads();
        if (tid < KP1) {
            float cs = 0.0f;
            #pragma unroll
            for (int g = 0; g < SLABR; g++) cs += slab[g * SLABS + tid];
            float nuj = (tid == KK) ? nu_last : inv_n;
            vprev_sh[tid] = v_sh[tid];           // keep vt_{199} for final u
            v_sh[tid] = nuj / cs;
        }
        __syncthreads();
    }

    // ---- final pass A: ut per row (vs v_prev) -> stash in srt (sort buf dead) ----
    {
        float vp[16], vp64;
        #pragma unroll
        for (int j = 0; j < 16; j++) vp[j] = vprev_sh[seg * 16 + j];
        vp64 = vprev_sh[64];
        #pragma unroll
        for (int pr = 0; pr < NPAIRS; pr++) {
            const float4 pw = pairs_sh[pr * (NTEAMS * 4) + team * 4 + seg];
            int rowA = team + NTEAMS * (2 * pr);
            int rowB = rowA + NTEAMS;
            float hA = vp[0], hB = vp[0];
            #pragma unroll
            for (int m = 1; m < 16; m++) {
                hA = fmaf(hA, pw.y, vp[m]);
                hB = fmaf(hB, pw.w, vp[m]);
            }
            float pA = hA * pw.x, pB = hB * pw.z;
            if (seg == 3) { pA += vp64; pB += vp64; }
            pA = DPP_ADD(pA, 0xB1); pB = DPP_ADD(pB, 0xB1);
            pA = DPP_ADD(pA, 0x4E); pB = DPP_ADD(pB, 0x4E);
            if (seg == 0) {
                srt[rowA] = inv_n / pA;
                srt[rowB] = inv_n / pB;
            }
        }
    }
    __syncthreads();

    // ---- final pass B: outputs + norm (runs once) ----
    {
        float vloc[16], v64;
        #pragma unroll
        for (int j = 0; j < 16; j++) vloc[j] = v_sh[seg * 16 + j];
        v64 = v_sh[64];

        double npart = 0.0;
        #pragma unroll 1
        for (int r = 0; r < ROWS_PT; r++) {
            int row = team + NTEAMS * r;
            int pr = r >> 1, isB = r & 1;
            const float4 pw = pairs_sh[pr * (NTEAMS * 4) + team * 4 + seg];
            float wv  = isB ? pw.w : pw.y;
            float wcv = isB ? pw.z : pw.x;
            float si = ss[row];
            float u  = srt[row];
            // Gamma row segment: gm[m] = ut * w^(64-16s-m) * vt[m]
            float gm[16];
            float ug = u * wcv;
            #pragma unroll
            for (int m = 15; m >= 0; m--) { gm[m] = ug * vloc[m]; ug *= wv; }

            float g0sum = 0.0f;
            float* orow = out + ((size_t)b * NN + row) * KK + seg * 16;
            #pragma unroll
            for (int q = 0; q < 4; q++) {
                float4 o;
                #define DO_K(kk_, fld) { const int kl = 4 * q + kk_;            \
                    float dd = fabsf(topk_sh[seg * 16 + kl] - si);              \
                    float e  = __builtin_amdgcn_exp2f(dd * lt);                 \
                    float sg = 1.0f / (1.0f + e) + 1e-20f;                      \
                    float g0 = (sg * recS_sh[seg * 16 + kl]) * inv_n;           \
                    g0sum += g0;                                                \
                    float df = gm[kl] - g0; npart += (double)df * (double)df;   \
                    o.fld = gm[kl] * 2048.0f; }
                DO_K(0, x) DO_K(1, y) DO_K(2, z) DO_K(3, w)
                #undef DO_K
                ((float4*)orow)[q] = o;
            }
            float gtot = g0sum;
            gtot = DPP_ADD(gtot, 0xB1);
            gtot = DPP_ADD(gtot, 0x4E);
            if (seg == 3) {
                float last = inv_n - gtot;
                last = fminf(fmaxf(last, 1e-20f), 1.0f - 1e-20f);   // clip
                float gm64 = u * v64;            // M_{i,64} = w^0 = 1
                float df = gm64 - last;
                npart += (double)df * (double)df;
            }
        }

        __syncthreads();
        red_sh[tid] = npart;
        __syncthreads();
        for (int s2 = NTHREADS / 2; s2 > 0; s2 >>= 1) {
            if (tid < s2) red_sh[tid] += red_sh[tid + s2];
            __syncthreads();
        }
        if (tid == 0) atomicAdd(norm_acc, red_sh[0]);
    }
}

// ---- kernel 3: finalize norm ----
__global__ void finalize_kernel(const double* __restrict__ norm_acc, float* __restrict__ out) {
    if (threadIdx.x == 0 && blockIdx.x == 0)
        out[(size_t)BS * NN * KK] = (float)sqrt(*norm_acc);
}

extern "C" void kernel_launch(void* const* d_in, const int* in_sizes, int n_in,
                              void* d_out, int out_size, void* d_ws, size_t ws_size,
                              hipStream_t stream) {
    const float* scores = (const float*)d_in[0];
    const float* W = (const float*)d_in[1];
    float* out = (float*)d_out;

    // ws layout: [0..3] max_enc(0), [4..7] inf_count(0),
    //            [8..15] norm_acc double(0), [16..19] min_enc(0xFFFFFFFF)
    unsigned* maxenc = (unsigned*)d_ws;
    unsigned* infc   = maxenc + 1;
    double*  nacc    = (double*)((char*)d_ws + 8);
    unsigned* minenc = (unsigned*)((char*)d_ws + 16);

    hipMemsetAsync(d_ws, 0, 16, stream);
    hipMemsetAsync((char*)d_ws + 16, 0xFF, 4, stream);

    hipLaunchKernelGGL(minmax_kernel, dim3(256), dim3(256), 0, stream,
                       scores, maxenc, minenc, infc);
    hipLaunchKernelGGL(sink_main, dim3(BS), dim3(NTHREADS), 0, stream,
                       scores, W, out, maxenc, minenc, infc, nacc);
    hipLaunchKernelGGL(finalize_kernel, dim3(1), dim3(64), 0, stream, nacc, out);
}

// Round 7
// 902.975 us; speedup vs baseline: 5.5062x; 1.1072x over previous
//
#include <hip/hip_runtime.h>
#include <math.h>

#define BS 256
#define NN 2048
#define KK 64
#define KP1 65
#define NTHREADS 1024
#define NTEAMS 256           // NTHREADS/4 teams; 4 lanes per team
#define ROWS_PT 8            // NN / NTEAMS rows per team
#define NPAIRS 4             // ROWS_PT/2 row-pairs per team
#define MAX_ITER 200
#define SLABR 32             // two slab rows per wave (one per 32-lane half)
#define SLABS 68             // slab row stride (floats): 16B-aligned rows

// cross-lane helpers that stay OFF the DS-bpermute path:
//   quad_perm xor1=0xB1, xor2=0x4E (VALU DPP); row_ror:8 = 0x128 == lane^8
//   within a 16-lane row (VALU DPP); ds_swizzle xor4=0x101F, xor16=0x401F
//   (DS, 1 op, no address VGPR, conflict-free permutation).
#define DPP_ADD(x, ctrl) ((x) + __int_as_float(__builtin_amdgcn_mov_dpp(      \
                              __float_as_int(x), (ctrl), 0xF, 0xF, true)))
#define SWZ_ADD(x, pat)  ((x) + __int_as_float(__builtin_amdgcn_ds_swizzle(   \
                              __float_as_int(x), (pat))))

// packed fp32 (VOP3P): 2x FP32 issue rate.  All operands must be 64-bit
// ALIGNED VGPR PAIRS (round-6 lesson: a lone VGPR + op_sel_hi is an invalid
// operand class).  Scalars are splatted to {b,b} pairs in C; the movs are
// loop-invariant per row-pair.
typedef float f2 __attribute__((ext_vector_type(2)));

__device__ __forceinline__ f2 pk_fma(f2 a, f2 b, f2 c) {   // a*b+c (packed)
    f2 d;
    asm("v_pk_fma_f32 %0, %1, %2, %3" : "=v"(d) : "v"(a), "v"(b), "v"(c));
    return d;
}
__device__ __forceinline__ f2 pk_mul(f2 a, f2 b) {          // a*b (packed)
    f2 d;
    asm("v_pk_mul_f32 %0, %1, %2" : "=v"(d) : "v"(a), "v"(b));
    return d;
}
__device__ __forceinline__ f2 pk_add(f2 a, f2 b) {
    f2 d;
    asm("v_pk_add_f32 %0, %1, %2" : "=v"(d) : "v"(a), "v"(b));
    return d;
}
__device__ __forceinline__ f2 splat2(float b) { f2 s; s.x = b; s.y = b; return s; }

// ---- monotone float<->uint encoding for atomic min/max ----
__device__ __forceinline__ unsigned enc_f32(float f) {
    unsigned b = __float_as_uint(f);
    return b ^ (unsigned)(((int)b >> 31) | (int)0x80000000);
}
__device__ __forceinline__ float dec_f32(unsigned e) {
    unsigned b = (e & 0x80000000u) ? (e & 0x7FFFFFFFu) : ~e;
    return __uint_as_float(b);
}

// ---- kernel 1: global min/max of scores (ignoring -inf for min), count -inf ----
__global__ void minmax_kernel(const float* __restrict__ s,
                              unsigned* __restrict__ maxenc,
                              unsigned* __restrict__ minenc,
                              unsigned* __restrict__ infc) {
    int tid = blockIdx.x * blockDim.x + threadIdx.x;
    int stride = gridDim.x * blockDim.x;
    float mx = -INFINITY, mn = INFINITY;
    unsigned cnt = 0;
    for (int i = tid; i < BS * NN; i += stride) {
        float v = s[i];
        if (isinf(v) && v < 0.0f) cnt++;
        else { mx = fmaxf(mx, v); mn = fminf(mn, v); }
    }
    for (int off = 32; off > 0; off >>= 1) {
        mx = fmaxf(mx, __shfl_down(mx, off));
        mn = fminf(mn, __shfl_down(mn, off));
        cnt += __shfl_down(cnt, off);
    }
    __shared__ float smx[8], smn[8];
    __shared__ unsigned scnt[8];
    int wid = threadIdx.x >> 6, lane = threadIdx.x & 63;
    if (lane == 0) { smx[wid] = mx; smn[wid] = mn; scnt[wid] = cnt; }
    __syncthreads();
    if (threadIdx.x == 0) {
        int nw = blockDim.x >> 6;
        for (int w = 1; w < nw; w++) { mx = fmaxf(mx, smx[w]); mn = fminf(mn, smn[w]); cnt += scnt[w]; }
        atomicMax(maxenc, enc_f32(mx));
        atomicMin(minenc, enc_f32(mn));
        if (cnt) atomicAdd(infc, cnt);
    }
}

// ---- kernel 2: per-batch sort + tau + Gamma0 + 200-iter Sinkhorn + outputs ----
// Factorization: Sinkhorn on M_ij = w_i^(64-j), w_i = exp2(-2*negc2*s_i), with
// vt0 = q/65 is exactly equivalent to the reference (ut=u*p, vt=q*v).
// ROUND-7 (= round-6 intent, asm fixed): kernel is VALU-issue-bound
// (VALUBusy 79%).  (a) Row sums use the even/odd Horner split
// P(w)=w*E(w^2)+O(w^2) with v_pk_fma_f32 (7 pk + 1 fma vs 15 fma); col sums
// pack adjacent columns (1 op/elem vs 2).  (b) The serial one-wave v-update
// tail is spread over 520 threads (8 lanes/col + DPP/swizzle tree).
__global__ void __launch_bounds__(NTHREADS)
sink_main(const float* __restrict__ scores, const float* __restrict__ W,
          float* __restrict__ out,
          const unsigned* __restrict__ maxenc, const unsigned* __restrict__ minenc,
          const unsigned* __restrict__ infc, double* __restrict__ norm_acc)
{
    const int tid  = threadIdx.x;
    const int b    = blockIdx.x;
    const int team = tid >> 2;     // 0..255
    const int seg  = tid & 3;      // 0..3
    const int wid  = tid >> 6;     // wave id 0..15
    const int lane = tid & 63;

    __shared__ float ss[NN];                                   // filled scores
    __shared__ float srt[NN];                                  // sort buf; later ut per row
    __shared__ float4 pairs_sh[NPAIRS * NTEAMS * 4];           // (wcA,wA,wcB,wB) per (pr,team,seg)
    __shared__ float v_sh[68] __attribute__((aligned(16)));    // vt (65 used)
    __shared__ float vprev_sh[68];                             // vt_{t-1}
    __shared__ float slab[SLABR * SLABS] __attribute__((aligned(16))); // per-half-wave partials
    __shared__ double red_sh[NTHREADS];
    __shared__ float recS_sh[KK];
    __shared__ float topk_sh[KK];

    const float LOG2E   = 1.4426950408889634f;
    const float inv_n   = 1.0f / 2048.0f;        // exact
    const float nu_last = 1984.0f / 2048.0f;     // exact

    // global scalars
    float smax = dec_f32(*maxenc);
    float smin = dec_f32(*minenc);
    unsigned icnt = *infc;
    float filled = smin - (smax - smin);
    float slo = (icnt > 0) ? filled : smin;
    // C.max() attained at an extreme s with anchor 0 or 64 (convexity)
    float cA = slo * slo, cB = (slo - 64.0f) * (slo - 64.0f);
    float cC = smax * smax, cD = (smax - 64.0f) * (smax - 64.0f);
    float Cmax = fmaxf(fmaxf(cA, cB), fmaxf(cC, cD));
    float negc2 = -(10.0f * LOG2E) / Cmax;       // exp(-C/Cmax/0.1) == exp2(d*d*negc2)
    float m2 = -2.0f * negc2;                    // w = exp2(m2 * s)

    // load + -inf fill
    for (int i = tid; i < NN; i += NTHREADS) {
        float v = scores[(size_t)b * NN + i];
        if (isinf(v) && v < 0.0f) v = filled;
        ss[i] = v; srt[i] = v;
    }
    __syncthreads();

    // bitonic sort (ascending); 1 pair per thread per substep
    for (int size = 2; size <= NN; size <<= 1) {
        for (int stride = size >> 1; stride > 0; stride >>= 1) {
            #pragma unroll
            for (int pp = 0; pp < (NN / 2) / NTHREADS; pp++) {
                int p = tid + pp * NTHREADS;
                int lo = ((p & ~(stride - 1)) << 1) | (p & (stride - 1));
                int hi = lo + stride;
                bool up = ((lo & size) == 0);
                float x = srt[lo], y = srt[hi];
                if ((x > y) == up) { srt[lo] = y; srt[hi] = x; }
            }
            __syncthreads();
        }
    }

    // topk (descending) from sorted
    for (int k = tid; k < KK; k += NTHREADS) topk_sh[k] = srt[NN - 1 - k];

    // tau = sum(sorted * W), fp64 accumulate
    double tp = 0.0;
    for (int i = tid; i < NN; i += NTHREADS) tp += (double)srt[i] * (double)W[i];
    red_sh[tid] = tp;
    __syncthreads();
    for (int s2 = NTHREADS / 2; s2 > 0; s2 >>= 1) {
        if (tid < s2) red_sh[tid] += red_sh[tid + s2];
        __syncthreads();
    }
    float tau = (float)red_sh[0];
    float lt = LOG2E / tau;                      // sigma = 1/(1+exp2(|d|*lt))

    // init vt0 = q/65 (q_j = exp2(negc2*(64-j)^2))
    if (tid < KP1) {
        float a = (float)(KK - tid);
        v_sh[tid] = __builtin_amdgcn_exp2f(negc2 * a * a) * (1.0f / 65.0f);
    }

    // pairs table: (wcA, wA, wcB, wB) per (pr, team, seg); wc = w^(49-16*seg)
    for (int item = tid; item < NPAIRS * NTEAMS * 4; item += NTHREADS) {
        int pr = item >> 10;                 // NTEAMS*4 = 1024
        int tm = (item >> 2) & (NTEAMS - 1);
        int sg = item & 3;
        int rowA = tm + NTEAMS * (2 * pr);
        int rowB = rowA + NTEAMS;
        float wA = __builtin_amdgcn_exp2f(m2 * ss[rowA]);
        float wB = __builtin_amdgcn_exp2f(m2 * ss[rowB]);
        float a2 = wA * wA, a4 = a2 * a2, a8 = a4 * a4, a16 = a8 * a8;
        float b2 = wB * wB, b4 = b2 * b2, b8 = b4 * b4, b16 = b8 * b8;
        float wcA = wA, wcB = wB;            // sg==3: w^1
        if (sg < 3) { wcA *= a16; wcB *= b16; }   // sg==2: w^17
        if (sg < 2) { wcA *= a16; wcB *= b16; }   // sg==1: w^33
        if (sg < 1) { wcA *= a16; wcB *= b16; }   // sg==0: w^49
        pairs_sh[item] = make_float4(wcA, wA, wcB, wB);
    }
    __syncthreads();

    const bool writer = ((lane & 0x1C) == 0);    // lanes 0-3 and 32-35
    const int  half   = lane >> 5;               // which 32-lane half
    const int  srow   = wid * 2 + half;          // this half's slab row

    // ---- Gamma0 column sums S_k: butterfly (xor4/8/16) + per-half slab row ----
    {
        float tk[16];
        #pragma unroll
        for (int kk = 0; kk < 16; kk++) tk[kk] = topk_sh[seg * 16 + kk];
        float part[16];
        #pragma unroll
        for (int kk = 0; kk < 16; kk++) part[kk] = 0.0f;
        #pragma unroll 1
        for (int r = 0; r < ROWS_PT; r++) {
            float si = ss[team + NTEAMS * r];
            #pragma unroll
            for (int kk = 0; kk < 16; kk++) {
                float d = fabsf(tk[kk] - si);
                float e = __builtin_amdgcn_exp2f(d * lt);
                part[kk] += 1.0f / (1.0f + e) + 1e-20f;
            }
        }
        #pragma unroll
        for (int kk = 0; kk < 16; kk++) {
            part[kk] = SWZ_ADD(part[kk], 0x101F);   // xor4
            part[kk] = DPP_ADD(part[kk], 0x128);    // xor8 (row_ror:8)
            part[kk] = SWZ_ADD(part[kk], 0x401F);   // xor16
        }
        if (writer) {
            float4* dst = (float4*)&slab[srow * SLABS + seg * 16];
            dst[0] = make_float4(part[0], part[1], part[2], part[3]);
            dst[1] = make_float4(part[4], part[5], part[6], part[7]);
            dst[2] = make_float4(part[8], part[9], part[10], part[11]);
            dst[3] = make_float4(part[12], part[13], part[14], part[15]);
        }
    }
    __syncthreads();
    if (tid < KK) {
        float sum = 0.0f;
        #pragma unroll
        for (int g = 0; g < SLABR; g++) sum += slab[g * SLABS + tid];
        recS_sh[tid] = 1.0f / sum;
    }
    __syncthreads();

    // ---- Sinkhorn: 200 iterations; packed-f32 Horner rows + packed col chain ----
    for (int t = 0; t < MAX_ITER; t++) {
        f2 vl2[8];                                // {v[2q], v[2q+1]} pairs
        float v64;
        #pragma unroll
        for (int q = 0; q < 4; q++) {
            float4 vv = ((const float4*)(v_sh + seg * 16))[q];
            vl2[2 * q + 0].x = vv.x; vl2[2 * q + 0].y = vv.y;
            vl2[2 * q + 1].x = vv.z; vl2[2 * q + 1].y = vv.w;
        }
        v64 = v_sh[64];
        f2 cpP[8];                                // {cp[2p], cp[2p+1]}
        #pragma unroll
        for (int p = 0; p < 8; p++) { cpP[p].x = 0.0f; cpP[p].y = 0.0f; }
        float c64 = 0.0f;

        #pragma unroll 2
        for (int pr = 0; pr < NPAIRS; pr++) {
            const float4 pw = pairs_sh[pr * (NTEAMS * 4) + team * 4 + seg];
            const float wcA = pw.x, wA = pw.y, wcB = pw.z, wB = pw.w;
            const f2 wA2p = splat2(wA * wA);
            const f2 wB2p = splat2(wB * wB);
            // row sums: even/odd Horner, P(w) = w*E(w^2) + O(w^2)
            f2 hA2 = vl2[0], hB2 = vl2[0];
            #pragma unroll
            for (int q = 1; q < 8; q++) {
                hA2 = pk_fma(hA2, wA2p, vl2[q]);
                hB2 = pk_fma(hB2, wB2p, vl2[q]);
            }
            float hA = fmaf(hA2.x, wA, hA2.y);
            float hB = fmaf(hB2.x, wB, hB2.y);
            float pA = hA * wcA, pB = hB * wcB;
            if (seg == 3) { pA += v64; pB += v64; }   // j=64 term, M=1
            pA = DPP_ADD(pA, 0xB1);                   // xor1 (quad_perm)
            pB = DPP_ADD(pB, 0xB1);
            pA = DPP_ADD(pA, 0x4E);                   // xor2 (quad_perm)
            pB = DPP_ADD(pB, 0x4E);
            float uA = inv_n / pA;               // IEEE div, matches ref
            float uB = inv_n / pB;
            // col sums, packed over adjacent cols: term(m) = wc*w^(15-m)*u
            float tclA = uA * wcA, tclB = uB * wcB;
            f2 tA, tB;
            tA.x = tclA * wA; tA.y = tclA;       // cols {2p, 2p+1} at p=7
            tB.x = tclB * wB; tB.y = tclB;
            #pragma unroll
            for (int p = 7; p >= 0; p--) {
                cpP[p] = pk_add(cpP[p], tA);
                cpP[p] = pk_add(cpP[p], tB);
                if (p) { tA = pk_mul(tA, wA2p); tB = pk_mul(tB, wB2p); }
            }
            if (seg == 3) c64 += uA + uB;        // col j=64: M=1
        }

        // cross-team reduce within each 32-lane half (team bits 2..4)
        #pragma unroll
        for (int p = 0; p < 8; p++) {
            float lo = cpP[p].x, hi = cpP[p].y;
            lo = SWZ_ADD(lo, 0x101F); lo = DPP_ADD(lo, 0x128); lo = SWZ_ADD(lo, 0x401F);
            hi = SWZ_ADD(hi, 0x101F); hi = DPP_ADD(hi, 0x128); hi = SWZ_ADD(hi, 0x401F);
            cpP[p].x = lo; cpP[p].y = hi;
        }
        c64 = SWZ_ADD(c64, 0x101F);
        c64 = DPP_ADD(c64, 0x128);
        c64 = SWZ_ADD(c64, 0x401F);
        if (writer) {
            float4* dst = (float4*)&slab[srow * SLABS + seg * 16];
            dst[0] = make_float4(cpP[0].x, cpP[0].y, cpP[1].x, cpP[1].y);
            dst[1] = make_float4(cpP[2].x, cpP[2].y, cpP[3].x, cpP[3].y);
            dst[2] = make_float4(cpP[4].x, cpP[4].y, cpP[5].x, cpP[5].y);
            dst[3] = make_float4(cpP[6].x, cpP[6].y, cpP[7].x, cpP[7].y);
            if (seg == 3) slab[srow * SLABS + 64] = c64;
        }
        __syncthreads();
        // v update: 8 lanes per column (4 slab reads each + 3-stage reduce)
        if (tid < 8 * KP1) {
            int col = tid >> 3, r8 = tid & 7;
            float cs = slab[r8 * SLABS + col]
                     + slab[(r8 + 8)  * SLABS + col]
                     + slab[(r8 + 16) * SLABS + col]
                     + slab[(r8 + 24) * SLABS + col];
            cs = DPP_ADD(cs, 0xB1);              // xor1
            cs = DPP_ADD(cs, 0x4E);              // xor2
            cs = SWZ_ADD(cs, 0x101F);            // xor4
            if (r8 == 0) {
                float nuj = (col == KK) ? nu_last : inv_n;
                vprev_sh[col] = v_sh[col];       // keep vt_{199} for final u
                v_sh[col] = nuj / cs;
            }
        }
        __syncthreads();
    }

    // ---- final pass A: ut per row (vs v_prev) -> stash in srt (sort buf dead) ----
    {
        float vp[16], vp64;
        #pragma unroll
        for (int j = 0; j < 16; j++) vp[j] = vprev_sh[seg * 16 + j];
        vp64 = vprev_sh[64];
        #pragma unroll
        for (int pr = 0; pr < NPAIRS; pr++) {
            const float4 pw = pairs_sh[pr * (NTEAMS * 4) + team * 4 + seg];
            int rowA = team + NTEAMS * (2 * pr);
            int rowB = rowA + NTEAMS;
            float hA = vp[0], hB = vp[0];
            #pragma unroll
            for (int m = 1; m < 16; m++) {
                hA = fmaf(hA, pw.y, vp[m]);
                hB = fmaf(hB, pw.w, vp[m]);
            }
            float pA = hA * pw.x, pB = hB * pw.z;
            if (seg == 3) { pA += vp64; pB += vp64; }
            pA = DPP_ADD(pA, 0xB1); pB = DPP_ADD(pB, 0xB1);
            pA = DPP_ADD(pA, 0x4E); pB = DPP_ADD(pB, 0x4E);
            if (seg == 0) {
                srt[rowA] = inv_n / pA;
                srt[rowB] = inv_n / pB;
            }
        }
    }
    __syncthreads();

    // ---- final pass B: outputs + norm (runs once) ----
    {
        float vloc[16], v64;
        #pragma unroll
        for (int j = 0; j < 16; j++) vloc[j] = v_sh[seg * 16 + j];
        v64 = v_sh[64];

        double npart = 0.0;
        #pragma unroll 1
        for (int r = 0; r < ROWS_PT; r++) {
            int row = team + NTEAMS * r;
            int pr = r >> 1, isB = r & 1;
            const float4 pw = pairs_sh[pr * (NTEAMS * 4) + team * 4 + seg];
            float wv  = isB ? pw.w : pw.y;
            float wcv = isB ? pw.z : pw.x;
            float si = ss[row];
            float u  = srt[row];
            // Gamma row segment: gm[m] = ut * w^(64-16s-m) * vt[m]
            float gm[16];
            float ug = u * wcv;
            #pragma unroll
            for (int m = 15; m >= 0; m--) { gm[m] = ug * vloc[m]; ug *= wv; }

            float g0sum = 0.0f;
            float* orow = out + ((size_t)b * NN + row) * KK + seg * 16;
            #pragma unroll
            for (int q = 0; q < 4; q++) {
                float4 o;
                #define DO_K(kk_, fld) { const int kl = 4 * q + kk_;            \
                    float dd = fabsf(topk_sh[seg * 16 + kl] - si);              \
                    float e  = __builtin_amdgcn_exp2f(dd * lt);                 \
                    float sg = 1.0f / (1.0f + e) + 1e-20f;                      \
                    float g0 = (sg * recS_sh[seg * 16 + kl]) * inv_n;           \
                    g0sum += g0;                                                \
                    float df = gm[kl] - g0; npart += (double)df * (double)df;   \
                    o.fld = gm[kl] * 2048.0f; }
                DO_K(0, x) DO_K(1, y) DO_K(2, z) DO_K(3, w)
                #undef DO_K
                ((float4*)orow)[q] = o;
            }
            float gtot = g0sum;
            gtot = DPP_ADD(gtot, 0xB1);
            gtot = DPP_ADD(gtot, 0x4E);
            if (seg == 3) {
                float last = inv_n - gtot;
                last = fminf(fmaxf(last, 1e-20f), 1.0f - 1e-20f);   // clip
                float gm64 = u * v64;            // M_{i,64} = w^0 = 1
                float df = gm64 - last;
                npart += (double)df * (double)df;
            }
        }

        __syncthreads();
        red_sh[tid] = npart;
        __syncthreads();
        for (int s2 = NTHREADS / 2; s2 > 0; s2 >>= 1) {
            if (tid < s2) red_sh[tid] += red_sh[tid + s2];
            __syncthreads();
        }
        if (tid == 0) atomicAdd(norm_acc, red_sh[0]);
    }
}

// ---- kernel 3: finalize norm ----
__global__ void finalize_kernel(const double* __restrict__ norm_acc, float* __restrict__ out) {
    if (threadIdx.x == 0 && blockIdx.x == 0)
        out[(size_t)BS * NN * KK] = (float)sqrt(*norm_acc);
}

extern "C" void kernel_launch(void* const* d_in, const int* in_sizes, int n_in,
                              void* d_out, int out_size, void* d_ws, size_t ws_size,
                              hipStream_t stream) {
    const float* scores = (const float*)d_in[0];
    const float* W = (const float*)d_in[1];
    float* out = (float*)d_out;

    // ws layout: [0..3] max_enc(0), [4..7] inf_count(0),
    //            [8..15] norm_acc double(0), [16..19] min_enc(0xFFFFFFFF)
    unsigned* maxenc = (unsigned*)d_ws;
    unsigned* infc   = maxenc + 1;
    double*  nacc    = (double*)((char*)d_ws + 8);
    unsigned* minenc = (unsigned*)((char*)d_ws + 16);

    hipMemsetAsync(d_ws, 0, 16, stream);
    hipMemsetAsync((char*)d_ws + 16, 0xFF, 4, stream);

    hipLaunchKernelGGL(minmax_kernel, dim3(256), dim3(256), 0, stream,
                       scores, maxenc, minenc, infc);
    hipLaunchKernelGGL(sink_main, dim3(BS), dim3(NTHREADS), 0, stream,
                       scores, W, out, maxenc, minenc, infc, nacc);
    hipLaunchKernelGGL(finalize_kernel, dim3(1), dim3(64), 0, stream, nacc, out);
}

// Round 8
// 829.587 us; speedup vs baseline: 5.9933x; 1.0885x over previous
//
#include <hip/hip_runtime.h>
#include <math.h>

#define BS 256
#define NN 2048
#define KK 64
#define KP1 65
#define NTHREADS 1024
#define NTEAMS 256           // NTHREADS/4 teams; 4 lanes per team
#define ROWS_PT 8            // NN / NTEAMS rows per team
#define NPAIRS 4             // ROWS_PT/2 row-pairs per team
#define MAX_ITER 200
#define SLABR 32             // two slab rows per wave (one per 32-lane half)
#define SLABS 68             // slab row stride (floats): 16B-aligned rows

// cross-lane helpers off the DS-bpermute path:
//   quad_perm xor1=0xB1, xor2=0x4E, bcast-lane-p=p*0x55 (VALU DPP);
//   row_ror:8 = 0x128 == lane^8 within a 16-lane row (VALU DPP);
//   ds_swizzle xor4=0x101F, xor16=0x401F (DS, 1 op, no addr VGPR).
#define DPP_ADD(x, ctrl) ((x) + __int_as_float(__builtin_amdgcn_mov_dpp(      \
                              __float_as_int(x), (ctrl), 0xF, 0xF, true)))
#define SWZ_ADD(x, pat)  ((x) + __int_as_float(__builtin_amdgcn_ds_swizzle(   \
                              __float_as_int(x), (pat))))
#define DPPF(x, ctrl) __int_as_float(__builtin_amdgcn_mov_dpp(                \
                              __float_as_int(x), (ctrl), 0xF, 0xF, true))
#define SWZF(x, pat)  __int_as_float(__builtin_amdgcn_ds_swizzle(             \
                              __float_as_int(x), (pat)))

// packed fp32 (VOP3P), 2x FP32 issue rate.  Round-8: TIED accumulator
// constraints ("+v", dst==src) so the allocator doesn't insert pair-moves
// around every asm block (round-7 post-mortem: ~2x hidden mov mass).
typedef float f2 __attribute__((ext_vector_type(2)));

__device__ __forceinline__ void pk_fma_acc(f2& h, f2 m, f2 a) {  // h = h*m + a
    asm("v_pk_fma_f32 %0, %0, %1, %2" : "+v"(h) : "v"(m), "v"(a));
}
__device__ __forceinline__ void pk_add_acc(f2& acc, f2 t) {      // acc += t
    asm("v_pk_add_f32 %0, %0, %1" : "+v"(acc) : "v"(t));
}
__device__ __forceinline__ void pk_mul_acc(f2& t, f2 m) {        // t *= m
    asm("v_pk_mul_f32 %0, %0, %1" : "+v"(t) : "v"(m));
}
__device__ __forceinline__ f2 pk_add(f2 a, f2 b) {
    f2 d;
    asm("v_pk_add_f32 %0, %1, %2" : "=v"(d) : "v"(a), "v"(b));
    return d;
}
__device__ __forceinline__ f2 splat2(float b) { f2 s; s.x = b; s.y = b; return s; }

// broadcast lane p of each 4-lane quad (compile-time p via switch: mov_dpp
// ctrl must be an integer constant expression)
__device__ __forceinline__ float quad_bcast(float v, int pr) {
    int i = __float_as_int(v), r;
    switch (pr & 3) {
        case 0:  r = __builtin_amdgcn_mov_dpp(i, 0x00, 0xF, 0xF, true); break;
        case 1:  r = __builtin_amdgcn_mov_dpp(i, 0x55, 0xF, 0xF, true); break;
        case 2:  r = __builtin_amdgcn_mov_dpp(i, 0xAA, 0xF, 0xF, true); break;
        default: r = __builtin_amdgcn_mov_dpp(i, 0xFF, 0xF, 0xF, true); break;
    }
    return __int_as_float(r);
}

// packed 3-stage cross-team reduce within a 32-lane half (xor4, xor8, xor16);
// per-component op order identical to round 7 (bit-exact).
__device__ __forceinline__ f2 half_reduce(f2 v) {
    f2 t;
    t.x = SWZF(v.x, 0x101F); t.y = SWZF(v.y, 0x101F); v = pk_add(v, t);
    t.x = DPPF(v.x, 0x128);  t.y = DPPF(v.y, 0x128);  v = pk_add(v, t);
    t.x = SWZF(v.x, 0x401F); t.y = SWZF(v.y, 0x401F); v = pk_add(v, t);
    return v;
}

// ---- monotone float<->uint encoding for atomic min/max ----
__device__ __forceinline__ unsigned enc_f32(float f) {
    unsigned b = __float_as_uint(f);
    return b ^ (unsigned)(((int)b >> 31) | (int)0x80000000);
}
__device__ __forceinline__ float dec_f32(unsigned e) {
    unsigned b = (e & 0x80000000u) ? (e & 0x7FFFFFFFu) : ~e;
    return __uint_as_float(b);
}

// ---- kernel 1: global min/max of scores (ignoring -inf for min), count -inf ----
__global__ void minmax_kernel(const float* __restrict__ s,
                              unsigned* __restrict__ maxenc,
                              unsigned* __restrict__ minenc,
                              unsigned* __restrict__ infc) {
    int tid = blockIdx.x * blockDim.x + threadIdx.x;
    int stride = gridDim.x * blockDim.x;
    float mx = -INFINITY, mn = INFINITY;
    unsigned cnt = 0;
    for (int i = tid; i < BS * NN; i += stride) {
        float v = s[i];
        if (isinf(v) && v < 0.0f) cnt++;
        else { mx = fmaxf(mx, v); mn = fminf(mn, v); }
    }
    for (int off = 32; off > 0; off >>= 1) {
        mx = fmaxf(mx, __shfl_down(mx, off));
        mn = fminf(mn, __shfl_down(mn, off));
        cnt += __shfl_down(cnt, off);
    }
    __shared__ float smx[8], smn[8];
    __shared__ unsigned scnt[8];
    int wid = threadIdx.x >> 6, lane = threadIdx.x & 63;
    if (lane == 0) { smx[wid] = mx; smn[wid] = mn; scnt[wid] = cnt; }
    __syncthreads();
    if (threadIdx.x == 0) {
        int nw = blockDim.x >> 6;
        for (int w = 1; w < nw; w++) { mx = fmaxf(mx, smx[w]); mn = fminf(mn, smn[w]); cnt += scnt[w]; }
        atomicMax(maxenc, enc_f32(mx));
        atomicMin(minenc, enc_f32(mn));
        if (cnt) atomicAdd(infc, cnt);
    }
}

// ---- kernel 2: per-batch sort + tau + Gamma0 + 200-iter Sinkhorn + outputs ----
// Factorization: Sinkhorn on M_ij = w_i^(64-j), w_i = exp2(-2*negc2*s_i), with
// vt0 = q/65 is exactly equivalent to the reference (ut=u*p, vt=q*v).
// ROUND-8: still VALU-issue-bound (VALUBusy 81%).  Cuts, all bit-exact:
// (1) the 8 redundant per-team IEEE divides -> 2 lane-distributed divides
//     (row-phase keeps pair seg's sums via cndmask; col-phase re-broadcasts
//     u with mov_dpp quad_perm bcast) -- division values identical;
// (2) tied "+v" asm accumulators (no copy movs around pk ops);
// (3) packed f2 butterfly + first-pair cpP init ((0+tA)+tB == tA+tB).
__global__ void __launch_bounds__(NTHREADS)
sink_main(const float* __restrict__ scores, const float* __restrict__ W,
          float* __restrict__ out,
          const unsigned* __restrict__ maxenc, const unsigned* __restrict__ minenc,
          const unsigned* __restrict__ infc, double* __restrict__ norm_acc)
{
    const int tid  = threadIdx.x;
    const int b    = blockIdx.x;
    const int team = tid >> 2;     // 0..255
    const int seg  = tid & 3;      // 0..3
    const int wid  = tid >> 6;     // wave id 0..15
    const int lane = tid & 63;

    __shared__ float ss[NN];                                   // filled scores
    __shared__ float srt[NN];                                  // sort buf; later ut per row
    __shared__ float4 pairs_sh[NPAIRS * NTEAMS * 4];           // (wcA,wA,wcB,wB) per (pr,team,seg)
    __shared__ float v_sh[68] __attribute__((aligned(16)));    // vt (65 used)
    __shared__ float vprev_sh[68];                             // vt_{t-1}
    __shared__ float slab[SLABR * SLABS] __attribute__((aligned(16))); // per-half-wave partials
    __shared__ double red_sh[NTHREADS];
    __shared__ float recS_sh[KK];
    __shared__ float topk_sh[KK];

    const float LOG2E   = 1.4426950408889634f;
    const float inv_n   = 1.0f / 2048.0f;        // exact
    const float nu_last = 1984.0f / 2048.0f;     // exact

    // global scalars
    float smax = dec_f32(*maxenc);
    float smin = dec_f32(*minenc);
    unsigned icnt = *infc;
    float filled = smin - (smax - smin);
    float slo = (icnt > 0) ? filled : smin;
    // C.max() attained at an extreme s with anchor 0 or 64 (convexity)
    float cA = slo * slo, cB = (slo - 64.0f) * (slo - 64.0f);
    float cC = smax * smax, cD = (smax - 64.0f) * (smax - 64.0f);
    float Cmax = fmaxf(fmaxf(cA, cB), fmaxf(cC, cD));
    float negc2 = -(10.0f * LOG2E) / Cmax;       // exp(-C/Cmax/0.1) == exp2(d*d*negc2)
    float m2 = -2.0f * negc2;                    // w = exp2(m2 * s)

    // load + -inf fill
    for (int i = tid; i < NN; i += NTHREADS) {
        float v = scores[(size_t)b * NN + i];
        if (isinf(v) && v < 0.0f) v = filled;
        ss[i] = v; srt[i] = v;
    }
    __syncthreads();

    // bitonic sort (ascending); 1 pair per thread per substep
    for (int size = 2; size <= NN; size <<= 1) {
        for (int stride = size >> 1; stride > 0; stride >>= 1) {
            #pragma unroll
            for (int pp = 0; pp < (NN / 2) / NTHREADS; pp++) {
                int p = tid + pp * NTHREADS;
                int lo = ((p & ~(stride - 1)) << 1) | (p & (stride - 1));
                int hi = lo + stride;
                bool up = ((lo & size) == 0);
                float x = srt[lo], y = srt[hi];
                if ((x > y) == up) { srt[lo] = y; srt[hi] = x; }
            }
            __syncthreads();
        }
    }

    // topk (descending) from sorted
    for (int k = tid; k < KK; k += NTHREADS) topk_sh[k] = srt[NN - 1 - k];

    // tau = sum(sorted * W), fp64 accumulate
    double tp = 0.0;
    for (int i = tid; i < NN; i += NTHREADS) tp += (double)srt[i] * (double)W[i];
    red_sh[tid] = tp;
    __syncthreads();
    for (int s2 = NTHREADS / 2; s2 > 0; s2 >>= 1) {
        if (tid < s2) red_sh[tid] += red_sh[tid + s2];
        __syncthreads();
    }
    float tau = (float)red_sh[0];
    float lt = LOG2E / tau;                      // sigma = 1/(1+exp2(|d|*lt))

    // init vt0 = q/65 (q_j = exp2(negc2*(64-j)^2))
    if (tid < KP1) {
        float a = (float)(KK - tid);
        v_sh[tid] = __builtin_amdgcn_exp2f(negc2 * a * a) * (1.0f / 65.0f);
    }

    // pairs table: (wcA, wA, wcB, wB) per (pr, team, seg); wc = w^(49-16*seg)
    for (int item = tid; item < NPAIRS * NTEAMS * 4; item += NTHREADS) {
        int pr = item >> 10;                 // NTEAMS*4 = 1024
        int tm = (item >> 2) & (NTEAMS - 1);
        int sg = item & 3;
        int rowA = tm + NTEAMS * (2 * pr);
        int rowB = rowA + NTEAMS;
        float wA = __builtin_amdgcn_exp2f(m2 * ss[rowA]);
        float wB = __builtin_amdgcn_exp2f(m2 * ss[rowB]);
        float a2 = wA * wA, a4 = a2 * a2, a8 = a4 * a4, a16 = a8 * a8;
        float b2 = wB * wB, b4 = b2 * b2, b8 = b4 * b4, b16 = b8 * b8;
        float wcA = wA, wcB = wB;            // sg==3: w^1
        if (sg < 3) { wcA *= a16; wcB *= b16; }   // sg==2: w^17
        if (sg < 2) { wcA *= a16; wcB *= b16; }   // sg==1: w^33
        if (sg < 1) { wcA *= a16; wcB *= b16; }   // sg==0: w^49
        pairs_sh[item] = make_float4(wcA, wA, wcB, wB);
    }
    __syncthreads();

    const bool writer = ((lane & 0x1C) == 0);    // lanes 0-3 and 32-35
    const int  half   = lane >> 5;               // which 32-lane half
    const int  srow   = wid * 2 + half;          // this half's slab row

    // ---- Gamma0 column sums S_k: butterfly (xor4/8/16) + per-half slab row ----
    {
        float tk[16];
        #pragma unroll
        for (int kk = 0; kk < 16; kk++) tk[kk] = topk_sh[seg * 16 + kk];
        float part[16];
        #pragma unroll
        for (int kk = 0; kk < 16; kk++) part[kk] = 0.0f;
        #pragma unroll 1
        for (int r = 0; r < ROWS_PT; r++) {
            float si = ss[team + NTEAMS * r];
            #pragma unroll
            for (int kk = 0; kk < 16; kk++) {
                float d = fabsf(tk[kk] - si);
                float e = __builtin_amdgcn_exp2f(d * lt);
                part[kk] += 1.0f / (1.0f + e) + 1e-20f;
            }
        }
        #pragma unroll
        for (int kk = 0; kk < 16; kk++) {
            part[kk] = SWZ_ADD(part[kk], 0x101F);   // xor4
            part[kk] = DPP_ADD(part[kk], 0x128);    // xor8 (row_ror:8)
            part[kk] = SWZ_ADD(part[kk], 0x401F);   // xor16
        }
        if (writer) {
            float4* dst = (float4*)&slab[srow * SLABS + seg * 16];
            dst[0] = make_float4(part[0], part[1], part[2], part[3]);
            dst[1] = make_float4(part[4], part[5], part[6], part[7]);
            dst[2] = make_float4(part[8], part[9], part[10], part[11]);
            dst[3] = make_float4(part[12], part[13], part[14], part[15]);
        }
    }
    __syncthreads();
    if (tid < KK) {
        float sum = 0.0f;
        #pragma unroll
        for (int g = 0; g < SLABR; g++) sum += slab[g * SLABS + tid];
        recS_sh[tid] = 1.0f / sum;
    }
    __syncthreads();

    // ---- Sinkhorn: 200 iterations; two-phase (rows then cols) ----
    for (int t = 0; t < MAX_ITER; t++) {
        f2 vl2[8] __attribute__((aligned(16)));   // {v[2q], v[2q+1]} pairs
        #pragma unroll
        for (int q = 0; q < 4; q++)
            ((float4*)vl2)[q] = ((const float4*)(v_sh + seg * 16))[q];
        const float v64 = v_sh[64];
        const f2 v64p = splat2(v64);

        // phase 1: row sums (Horner) for all 4 pairs; lane keeps pair==seg
        f2 myP = splat2(1.0f);
        #pragma unroll
        for (int pr = 0; pr < NPAIRS; pr++) {
            const float4 pw = pairs_sh[pr * (NTEAMS * 4) + team * 4 + seg];
            const f2 wA2p = splat2(pw.y * pw.y);
            const f2 wB2p = splat2(pw.w * pw.w);
            f2 hA2 = vl2[0], hB2 = vl2[0];
            #pragma unroll
            for (int q = 1; q < 8; q++) {
                pk_fma_acc(hA2, wA2p, vl2[q]);    // h = h*w^2 + v[q]
                pk_fma_acc(hB2, wB2p, vl2[q]);
            }
            f2 pP;
            pP.x = fmaf(hA2.x, pw.y, hA2.y) * pw.x;
            pP.y = fmaf(hB2.x, pw.w, hB2.y) * pw.z;
            if (seg == 3) pP = pk_add(pP, v64p);  // j=64 term, M=1
            f2 tq;
            tq.x = DPPF(pP.x, 0xB1); tq.y = DPPF(pP.y, 0xB1); // xor1
            pP = pk_add(pP, tq);
            tq.x = DPPF(pP.x, 0x4E); tq.y = DPPF(pP.y, 0x4E); // xor2
            pP = pk_add(pP, tq);
            myP.x = (seg == pr) ? pP.x : myP.x;   // keep my pair's sums
            myP.y = (seg == pr) ? pP.y : myP.y;
        }
        const float uAm = inv_n / myP.x;          // 2 IEEE divs (was 8),
        const float uBm = inv_n / myP.y;          // values bit-identical

        // phase 2: col sums (geometric chain), u re-broadcast per pair
        f2 cpP[8];
        float c64 = 0.0f;
        #pragma unroll
        for (int pr = 0; pr < NPAIRS; pr++) {
            const float uA = quad_bcast(uAm, pr);
            const float uB = quad_bcast(uBm, pr);
            const float4 pw = pairs_sh[pr * (NTEAMS * 4) + team * 4 + seg];
            const f2 wA2p = splat2(pw.y * pw.y);
            const f2 wB2p = splat2(pw.w * pw.w);
            float tclA = uA * pw.x, tclB = uB * pw.z;
            f2 tA, tB;
            tA.x = tclA * pw.y; tA.y = tclA;      // cols {2p, 2p+1} at p=7
            tB.x = tclB * pw.w; tB.y = tclB;
            if (pr == 0) {
                #pragma unroll
                for (int p = 7; p >= 0; p--) {
                    cpP[p] = pk_add(tA, tB);      // == (0+tA)+tB bit-exact
                    if (p) { pk_mul_acc(tA, wA2p); pk_mul_acc(tB, wB2p); }
                }
            } else {
                #pragma unroll
                for (int p = 7; p >= 0; p--) {
                    pk_add_acc(cpP[p], tA);
                    pk_add_acc(cpP[p], tB);
                    if (p) { pk_mul_acc(tA, wA2p); pk_mul_acc(tB, wB2p); }
                }
            }
            if (seg == 3) c64 += uA + uB;         // col j=64: M=1
        }

        // cross-team reduce within each 32-lane half (packed)
        #pragma unroll
        for (int p = 0; p < 8; p++) cpP[p] = half_reduce(cpP[p]);
        c64 = SWZ_ADD(c64, 0x101F);
        c64 = DPP_ADD(c64, 0x128);
        c64 = SWZ_ADD(c64, 0x401F);
        if (writer) {
            float4* dst = (float4*)&slab[srow * SLABS + seg * 16];
            dst[0] = make_float4(cpP[0].x, cpP[0].y, cpP[1].x, cpP[1].y);
            dst[1] = make_float4(cpP[2].x, cpP[2].y, cpP[3].x, cpP[3].y);
            dst[2] = make_float4(cpP[4].x, cpP[4].y, cpP[5].x, cpP[5].y);
            dst[3] = make_float4(cpP[6].x, cpP[6].y, cpP[7].x, cpP[7].y);
            if (seg == 3) slab[srow * SLABS + 64] = c64;
        }
        __syncthreads();
        // v update: 8 lanes per column (4 slab reads each + 3-stage reduce)
        if (tid < 8 * KP1) {
            int col = tid >> 3, r8 = tid & 7;
            float cs = slab[r8 * SLABS + col]
                     + slab[(r8 + 8)  * SLABS + col]
                     + slab[(r8 + 16) * SLABS + col]
                     + slab[(r8 + 24) * SLABS + col];
            cs = DPP_ADD(cs, 0xB1);              // xor1
            cs = DPP_ADD(cs, 0x4E);              // xor2
            cs = SWZ_ADD(cs, 0x101F);            // xor4
            if (r8 == 0) {
                float nuj = (col == KK) ? nu_last : inv_n;
                vprev_sh[col] = v_sh[col];       // keep vt_{199} for final u
                v_sh[col] = nuj / cs;
            }
        }
        __syncthreads();
    }

    // ---- final pass A: ut per row (vs v_prev) -> stash in srt (sort buf dead) ----
    {
        float vp[16], vp64;
        #pragma unroll
        for (int j = 0; j < 16; j++) vp[j] = vprev_sh[seg * 16 + j];
        vp64 = vprev_sh[64];
        #pragma unroll
        for (int pr = 0; pr < NPAIRS; pr++) {
            const float4 pw = pairs_sh[pr * (NTEAMS * 4) + team * 4 + seg];
            int rowA = team + NTEAMS * (2 * pr);
            int rowB = rowA + NTEAMS;
            float hA = vp[0], hB = vp[0];
            #pragma unroll
            for (int m = 1; m < 16; m++) {
                hA = fmaf(hA, pw.y, vp[m]);
                hB = fmaf(hB, pw.w, vp[m]);
            }
            float pA = hA * pw.x, pB = hB * pw.z;
            if (seg == 3) { pA += vp64; pB += vp64; }
            pA = DPP_ADD(pA, 0xB1); pB = DPP_ADD(pB, 0xB1);
            pA = DPP_ADD(pA, 0x4E); pB = DPP_ADD(pB, 0x4E);
            if (seg == 0) {
                srt[rowA] = inv_n / pA;
                srt[rowB] = inv_n / pB;
            }
        }
    }
    __syncthreads();

    // ---- final pass B: outputs + norm (runs once) ----
    {
        float vloc[16], v64;
        #pragma unroll
        for (int j = 0; j < 16; j++) vloc[j] = v_sh[seg * 16 + j];
        v64 = v_sh[64];

        double npart = 0.0;
        #pragma unroll 1
        for (int r = 0; r < ROWS_PT; r++) {
            int row = team + NTEAMS * r;
            int pr = r >> 1, isB = r & 1;
            const float4 pw = pairs_sh[pr * (NTEAMS * 4) + team * 4 + seg];
            float wv  = isB ? pw.w : pw.y;
            float wcv = isB ? pw.z : pw.x;
            float si = ss[row];
            float u  = srt[row];
            // Gamma row segment: gm[m] = ut * w^(64-16s-m) * vt[m]
            float gm[16];
            float ug = u * wcv;
            #pragma unroll
            for (int m = 15; m >= 0; m--) { gm[m] = ug * vloc[m]; ug *= wv; }

            float g0sum = 0.0f;
            float* orow = out + ((size_t)b * NN + row) * KK + seg * 16;
            #pragma unroll
            for (int q = 0; q < 4; q++) {
                float4 o;
                #define DO_K(kk_, fld) { const int kl = 4 * q + kk_;            \
                    float dd = fabsf(topk_sh[seg * 16 + kl] - si);              \
                    float e  = __builtin_amdgcn_exp2f(dd * lt);                 \
                    float sg = 1.0f / (1.0f + e) + 1e-20f;                      \
                    float g0 = (sg * recS_sh[seg * 16 + kl]) * inv_n;           \
                    g0sum += g0;                                                \
                    float df = gm[kl] - g0; npart += (double)df * (double)df;   \
                    o.fld = gm[kl] * 2048.0f; }
                DO_K(0, x) DO_K(1, y) DO_K(2, z) DO_K(3, w)
                #undef DO_K
                ((float4*)orow)[q] = o;
            }
            float gtot = g0sum;
            gtot = DPP_ADD(gtot, 0xB1);
            gtot = DPP_ADD(gtot, 0x4E);
            if (seg == 3) {
                float last = inv_n - gtot;
                last = fminf(fmaxf(last, 1e-20f), 1.0f - 1e-20f);   // clip
                float gm64 = u * v64;            // M_{i,64} = w^0 = 1
                float df = gm64 - last;
                npart += (double)df * (double)df;
            }
        }

        __syncthreads();
        red_sh[tid] = npart;
        __syncthreads();
        for (int s2 = NTHREADS / 2; s2 > 0; s2 >>= 1) {
            if (tid < s2) red_sh[tid] += red_sh[tid + s2];
            __syncthreads();
        }
        if (tid == 0) atomicAdd(norm_acc, red_sh[0]);
    }
}

// ---- kernel 3: finalize norm ----
__global__ void finalize_kernel(const double* __restrict__ norm_acc, float* __restrict__ out) {
    if (threadIdx.x == 0 && blockIdx.x == 0)
        out[(size_t)BS * NN * KK] = (float)sqrt(*norm_acc);
}

extern "C" void kernel_launch(void* const* d_in, const int* in_sizes, int n_in,
                              void* d_out, int out_size, void* d_ws, size_t ws_size,
                              hipStream_t stream) {
    const float* scores = (const float*)d_in[0];
    const float* W = (const float*)d_in[1];
    float* out = (float*)d_out;

    // ws layout: [0..3] max_enc(0), [4..7] inf_count(0),
    //            [8..15] norm_acc double(0), [16..19] min_enc(0xFFFFFFFF)
    unsigned* maxenc = (unsigned*)d_ws;
    unsigned* infc   = maxenc + 1;
    double*  nacc    = (double*)((char*)d_ws + 8);
    unsigned* minenc = (unsigned*)((char*)d_ws + 16);

    hipMemsetAsync(d_ws, 0, 16, stream);
    hipMemsetAsync((char*)d_ws + 16, 0xFF, 4, stream);

    hipLaunchKernelGGL(minmax_kernel, dim3(256), dim3(256), 0, stream,
                       scores, maxenc, minenc, infc);
    hipLaunchKernelGGL(sink_main, dim3(BS), dim3(NTHREADS), 0, stream,
                       scores, W, out, maxenc, minenc, infc, nacc);
    hipLaunchKernelGGL(finalize_kernel, dim3(1), dim3(64), 0, stream, nacc, out);
}

// Round 9
// 792.115 us; speedup vs baseline: 6.2768x; 1.0473x over previous
//
#include <hip/hip_runtime.h>
#include <math.h>

#define BS 256
#define NN 2048
#define KK 64
#define KP1 65
#define NTHREADS 1024
#define NTEAMS 256           // NTHREADS/4 teams; 4 lanes per team
#define ROWS_PT 8            // NN / NTEAMS rows per team
#define NPAIRS 4             // ROWS_PT/2 row-pairs per team
#define MAX_ITER 200
#define SLABR 32             // two slab rows per wave (one per 32-lane half)
#define SLABS 68             // slab row stride (floats): 16B-aligned rows

// cross-lane helpers off the DS-bpermute path:
//   quad_perm xor1=0xB1, xor2=0x4E, bcast-lane-p=p*0x55 (VALU DPP);
//   row_ror:8 = 0x128 == lane^8 within a 16-lane row (VALU DPP);
//   ds_swizzle xor4=0x101F, xor16=0x401F (DS, 1 op, no addr VGPR).
#define DPP_ADD(x, ctrl) ((x) + __int_as_float(__builtin_amdgcn_mov_dpp(      \
                              __float_as_int(x), (ctrl), 0xF, 0xF, true)))
#define SWZ_ADD(x, pat)  ((x) + __int_as_float(__builtin_amdgcn_ds_swizzle(   \
                              __float_as_int(x), (pat))))
#define DPPF(x, ctrl) __int_as_float(__builtin_amdgcn_mov_dpp(                \
                              __float_as_int(x), (ctrl), 0xF, 0xF, true))
#define SWZF(x, pat)  __int_as_float(__builtin_amdgcn_ds_swizzle(             \
                              __float_as_int(x), (pat)))

// packed fp32: ROUND-9 — native <2 x float> ops instead of inline asm.
// gfx950 has FeaturePackedFP32Ops: LLVM selects v_pk_{fma,add,mul}_f32 from
// vector IR, with full regalloc/scheduling freedom (round-8 post-mortem:
// asm pair-constraints generated ~2x hidden copy movs at the 56-VGPR cap).
// Bit-exact: IEEE per component, fma explicit.
typedef float f2 __attribute__((ext_vector_type(2)));

#if __has_builtin(__builtin_elementwise_fma)
__device__ __forceinline__ f2 pkfma(f2 a, f2 b, f2 c) {
    return __builtin_elementwise_fma(a, b, c);
}
#else
__device__ __forceinline__ f2 pkfma(f2 a, f2 b, f2 c) {
    f2 d;
    asm("v_pk_fma_f32 %0, %1, %2, %3" : "=v"(d) : "v"(a), "v"(b), "v"(c));
    return d;
}
#endif
__device__ __forceinline__ f2 splat2(float b) { f2 s; s.x = b; s.y = b; return s; }

// broadcast lane p of each 4-lane quad (compile-time p via switch: mov_dpp
// ctrl must be an integer constant expression)
__device__ __forceinline__ float quad_bcast(float v, int pr) {
    int i = __float_as_int(v), r;
    switch (pr & 3) {
        case 0:  r = __builtin_amdgcn_mov_dpp(i, 0x00, 0xF, 0xF, true); break;
        case 1:  r = __builtin_amdgcn_mov_dpp(i, 0x55, 0xF, 0xF, true); break;
        case 2:  r = __builtin_amdgcn_mov_dpp(i, 0xAA, 0xF, 0xF, true); break;
        default: r = __builtin_amdgcn_mov_dpp(i, 0xFF, 0xF, 0xF, true); break;
    }
    return __int_as_float(r);
}

// packed 3-stage cross-team reduce within a 32-lane half (xor4, xor8, xor16);
// per-component op order identical to rounds 7/8 (bit-exact).
__device__ __forceinline__ f2 half_reduce(f2 v) {
    f2 t;
    t.x = SWZF(v.x, 0x101F); t.y = SWZF(v.y, 0x101F); v = v + t;
    t.x = DPPF(v.x, 0x128);  t.y = DPPF(v.y, 0x128);  v = v + t;
    t.x = SWZF(v.x, 0x401F); t.y = SWZF(v.y, 0x401F); v = v + t;
    return v;
}

// ---- monotone float<->uint encoding for atomic min/max ----
__device__ __forceinline__ unsigned enc_f32(float f) {
    unsigned b = __float_as_uint(f);
    return b ^ (unsigned)(((int)b >> 31) | (int)0x80000000);
}
__device__ __forceinline__ float dec_f32(unsigned e) {
    unsigned b = (e & 0x80000000u) ? (e & 0x7FFFFFFFu) : ~e;
    return __uint_as_float(b);
}

// ---- kernel 1: global min/max of scores (ignoring -inf for min), count -inf ----
__global__ void minmax_kernel(const float* __restrict__ s,
                              unsigned* __restrict__ maxenc,
                              unsigned* __restrict__ minenc,
                              unsigned* __restrict__ infc) {
    int tid = blockIdx.x * blockDim.x + threadIdx.x;
    int stride = gridDim.x * blockDim.x;
    float mx = -INFINITY, mn = INFINITY;
    unsigned cnt = 0;
    for (int i = tid; i < BS * NN; i += stride) {
        float v = s[i];
        if (isinf(v) && v < 0.0f) cnt++;
        else { mx = fmaxf(mx, v); mn = fminf(mn, v); }
    }
    for (int off = 32; off > 0; off >>= 1) {
        mx = fmaxf(mx, __shfl_down(mx, off));
        mn = fminf(mn, __shfl_down(mn, off));
        cnt += __shfl_down(cnt, off);
    }
    __shared__ float smx[8], smn[8];
    __shared__ unsigned scnt[8];
    int wid = threadIdx.x >> 6, lane = threadIdx.x & 63;
    if (lane == 0) { smx[wid] = mx; smn[wid] = mn; scnt[wid] = cnt; }
    __syncthreads();
    if (threadIdx.x == 0) {
        int nw = blockDim.x >> 6;
        for (int w = 1; w < nw; w++) { mx = fmaxf(mx, smx[w]); mn = fminf(mn, smn[w]); cnt += scnt[w]; }
        atomicMax(maxenc, enc_f32(mx));
        atomicMin(minenc, enc_f32(mn));
        if (cnt) atomicAdd(infc, cnt);
    }
}

// ---- kernel 2: per-batch sort + tau + Gamma0 + 200-iter Sinkhorn + outputs ----
// Factorization: Sinkhorn on M_ij = w_i^(64-j), w_i = exp2(-2*negc2*s_i), with
// vt0 = q/65 is exactly equivalent to the reference (ut=u*p, vt=q*v).
// Structure (rounds 4-8): butterfly + per-half-wave slab rows (no LDS atomic
// contention), DPP/swizzle cross-lane (no ds_bpermute), packed-f32 Horner row
// pass + packed geometric col chain, 2 lane-distributed IEEE divides/thread
// (row sums kept via cndmask, u re-broadcast via quad_perm), parallel 520-
// thread v-update tail.
__global__ void __launch_bounds__(NTHREADS)
sink_main(const float* __restrict__ scores, const float* __restrict__ W,
          float* __restrict__ out,
          const unsigned* __restrict__ maxenc, const unsigned* __restrict__ minenc,
          const unsigned* __restrict__ infc, double* __restrict__ norm_acc)
{
    const int tid  = threadIdx.x;
    const int b    = blockIdx.x;
    const int team = tid >> 2;     // 0..255
    const int seg  = tid & 3;      // 0..3
    const int wid  = tid >> 6;     // wave id 0..15
    const int lane = tid & 63;

    __shared__ float ss[NN];                                   // filled scores
    __shared__ float srt[NN];                                  // sort buf; later ut per row
    __shared__ float4 pairs_sh[NPAIRS * NTEAMS * 4];           // (wcA,wA,wcB,wB) per (pr,team,seg)
    __shared__ float v_sh[68] __attribute__((aligned(16)));    // vt (65 used)
    __shared__ float vprev_sh[68];                             // vt_{t-1}
    __shared__ float slab[SLABR * SLABS] __attribute__((aligned(16))); // per-half-wave partials
    __shared__ double red_sh[NTHREADS];
    __shared__ float recS_sh[KK];
    __shared__ float topk_sh[KK];

    const float LOG2E   = 1.4426950408889634f;
    const float inv_n   = 1.0f / 2048.0f;        // exact
    const float nu_last = 1984.0f / 2048.0f;     // exact

    // global scalars
    float smax = dec_f32(*maxenc);
    float smin = dec_f32(*minenc);
    unsigned icnt = *infc;
    float filled = smin - (smax - smin);
    float slo = (icnt > 0) ? filled : smin;
    // C.max() attained at an extreme s with anchor 0 or 64 (convexity)
    float cA = slo * slo, cB = (slo - 64.0f) * (slo - 64.0f);
    float cC = smax * smax, cD = (smax - 64.0f) * (smax - 64.0f);
    float Cmax = fmaxf(fmaxf(cA, cB), fmaxf(cC, cD));
    float negc2 = -(10.0f * LOG2E) / Cmax;       // exp(-C/Cmax/0.1) == exp2(d*d*negc2)
    float m2 = -2.0f * negc2;                    // w = exp2(m2 * s)

    // load + -inf fill
    for (int i = tid; i < NN; i += NTHREADS) {
        float v = scores[(size_t)b * NN + i];
        if (isinf(v) && v < 0.0f) v = filled;
        ss[i] = v; srt[i] = v;
    }
    __syncthreads();

    // bitonic sort (ascending); 1 pair per thread per substep
    for (int size = 2; size <= NN; size <<= 1) {
        for (int stride = size >> 1; stride > 0; stride >>= 1) {
            #pragma unroll
            for (int pp = 0; pp < (NN / 2) / NTHREADS; pp++) {
                int p = tid + pp * NTHREADS;
                int lo = ((p & ~(stride - 1)) << 1) | (p & (stride - 1));
                int hi = lo + stride;
                bool up = ((lo & size) == 0);
                float x = srt[lo], y = srt[hi];
                if ((x > y) == up) { srt[lo] = y; srt[hi] = x; }
            }
            __syncthreads();
        }
    }

    // topk (descending) from sorted
    for (int k = tid; k < KK; k += NTHREADS) topk_sh[k] = srt[NN - 1 - k];

    // tau = sum(sorted * W), fp64 accumulate
    double tp = 0.0;
    for (int i = tid; i < NN; i += NTHREADS) tp += (double)srt[i] * (double)W[i];
    red_sh[tid] = tp;
    __syncthreads();
    for (int s2 = NTHREADS / 2; s2 > 0; s2 >>= 1) {
        if (tid < s2) red_sh[tid] += red_sh[tid + s2];
        __syncthreads();
    }
    float tau = (float)red_sh[0];
    float lt = LOG2E / tau;                      // sigma = 1/(1+exp2(|d|*lt))

    // init vt0 = q/65 (q_j = exp2(negc2*(64-j)^2))
    if (tid < KP1) {
        float a = (float)(KK - tid);
        v_sh[tid] = __builtin_amdgcn_exp2f(negc2 * a * a) * (1.0f / 65.0f);
    }

    // pairs table: (wcA, wA, wcB, wB) per (pr, team, seg); wc = w^(49-16*seg)
    for (int item = tid; item < NPAIRS * NTEAMS * 4; item += NTHREADS) {
        int pr = item >> 10;                 // NTEAMS*4 = 1024
        int tm = (item >> 2) & (NTEAMS - 1);
        int sg = item & 3;
        int rowA = tm + NTEAMS * (2 * pr);
        int rowB = rowA + NTEAMS;
        float wA = __builtin_amdgcn_exp2f(m2 * ss[rowA]);
        float wB = __builtin_amdgcn_exp2f(m2 * ss[rowB]);
        float a2 = wA * wA, a4 = a2 * a2, a8 = a4 * a4, a16 = a8 * a8;
        float b2 = wB * wB, b4 = b2 * b2, b8 = b4 * b4, b16 = b8 * b8;
        float wcA = wA, wcB = wB;            // sg==3: w^1
        if (sg < 3) { wcA *= a16; wcB *= b16; }   // sg==2: w^17
        if (sg < 2) { wcA *= a16; wcB *= b16; }   // sg==1: w^33
        if (sg < 1) { wcA *= a16; wcB *= b16; }   // sg==0: w^49
        pairs_sh[item] = make_float4(wcA, wA, wcB, wB);
    }
    __syncthreads();

    const bool writer = ((lane & 0x1C) == 0);    // lanes 0-3 and 32-35
    const int  half   = lane >> 5;               // which 32-lane half
    const int  srow   = wid * 2 + half;          // this half's slab row

    // ---- Gamma0 column sums S_k: butterfly (xor4/8/16) + per-half slab row ----
    {
        float tk[16];
        #pragma unroll
        for (int kk = 0; kk < 16; kk++) tk[kk] = topk_sh[seg * 16 + kk];
        float part[16];
        #pragma unroll
        for (int kk = 0; kk < 16; kk++) part[kk] = 0.0f;
        #pragma unroll 1
        for (int r = 0; r < ROWS_PT; r++) {
            float si = ss[team + NTEAMS * r];
            #pragma unroll
            for (int kk = 0; kk < 16; kk++) {
                float d = fabsf(tk[kk] - si);
                float e = __builtin_amdgcn_exp2f(d * lt);
                part[kk] += 1.0f / (1.0f + e) + 1e-20f;
            }
        }
        #pragma unroll
        for (int kk = 0; kk < 16; kk++) {
            part[kk] = SWZ_ADD(part[kk], 0x101F);   // xor4
            part[kk] = DPP_ADD(part[kk], 0x128);    // xor8 (row_ror:8)
            part[kk] = SWZ_ADD(part[kk], 0x401F);   // xor16
        }
        if (writer) {
            float4* dst = (float4*)&slab[srow * SLABS + seg * 16];
            dst[0] = make_float4(part[0], part[1], part[2], part[3]);
            dst[1] = make_float4(part[4], part[5], part[6], part[7]);
            dst[2] = make_float4(part[8], part[9], part[10], part[11]);
            dst[3] = make_float4(part[12], part[13], part[14], part[15]);
        }
    }
    __syncthreads();
    if (tid < KK) {
        float sum = 0.0f;
        #pragma unroll
        for (int g = 0; g < SLABR; g++) sum += slab[g * SLABS + tid];
        recS_sh[tid] = 1.0f / sum;
    }
    __syncthreads();

    // ---- Sinkhorn: 200 iterations; two-phase (rows then cols) ----
    for (int t = 0; t < MAX_ITER; t++) {
        f2 vl2[8] __attribute__((aligned(16)));   // {v[2q], v[2q+1]} pairs
        #pragma unroll
        for (int q = 0; q < 4; q++)
            ((float4*)vl2)[q] = ((const float4*)(v_sh + seg * 16))[q];
        const float v64 = v_sh[64];
        const f2 v64p = splat2(v64);

        // phase 1: row sums (Horner) for all 4 pairs; lane keeps pair==seg
        f2 myP = splat2(1.0f);
        #pragma unroll
        for (int pr = 0; pr < NPAIRS; pr++) {
            const float4 pw = pairs_sh[pr * (NTEAMS * 4) + team * 4 + seg];
            const f2 wA2p = splat2(pw.y * pw.y);
            const f2 wB2p = splat2(pw.w * pw.w);
            f2 hA2 = vl2[0], hB2 = vl2[0];
            #pragma unroll
            for (int q = 1; q < 8; q++) {
                hA2 = pkfma(hA2, wA2p, vl2[q]);   // h = h*w^2 + v[q]
                hB2 = pkfma(hB2, wB2p, vl2[q]);
            }
            f2 pP;
            pP.x = fmaf(hA2.x, pw.y, hA2.y) * pw.x;
            pP.y = fmaf(hB2.x, pw.w, hB2.y) * pw.z;
            if (seg == 3) pP = pP + v64p;         // j=64 term, M=1
            f2 tq;
            tq.x = DPPF(pP.x, 0xB1); tq.y = DPPF(pP.y, 0xB1); // xor1
            pP = pP + tq;
            tq.x = DPPF(pP.x, 0x4E); tq.y = DPPF(pP.y, 0x4E); // xor2
            pP = pP + tq;
            myP.x = (seg == pr) ? pP.x : myP.x;   // keep my pair's sums
            myP.y = (seg == pr) ? pP.y : myP.y;
        }
        const float uAm = inv_n / myP.x;          // 2 IEEE divs (was 8),
        const float uBm = inv_n / myP.y;          // values bit-identical

        // phase 2: col sums (geometric chain), u re-broadcast per pair
        f2 cpP[8];
        float c64 = 0.0f;
        #pragma unroll
        for (int pr = 0; pr < NPAIRS; pr++) {
            const float uA = quad_bcast(uAm, pr);
            const float uB = quad_bcast(uBm, pr);
            const float4 pw = pairs_sh[pr * (NTEAMS * 4) + team * 4 + seg];
            const f2 wA2p = splat2(pw.y * pw.y);
            const f2 wB2p = splat2(pw.w * pw.w);
            float tclA = uA * pw.x, tclB = uB * pw.z;
            f2 tA, tB;
            tA.x = tclA * pw.y; tA.y = tclA;      // cols {2p, 2p+1} at p=7
            tB.x = tclB * pw.w; tB.y = tclB;
            if (pr == 0) {
                #pragma unroll
                for (int p = 7; p >= 0; p--) {
                    cpP[p] = tA + tB;             // == (0+tA)+tB bit-exact
                    if (p) { tA = tA * wA2p; tB = tB * wB2p; }
                }
            } else {
                #pragma unroll
                for (int p = 7; p >= 0; p--) {
                    cpP[p] = (cpP[p] + tA) + tB;
                    if (p) { tA = tA * wA2p; tB = tB * wB2p; }
                }
            }
            if (seg == 3) c64 += uA + uB;         // col j=64: M=1
        }

        // cross-team reduce within each 32-lane half (packed)
        #pragma unroll
        for (int p = 0; p < 8; p++) cpP[p] = half_reduce(cpP[p]);
        c64 = SWZ_ADD(c64, 0x101F);
        c64 = DPP_ADD(c64, 0x128);
        c64 = SWZ_ADD(c64, 0x401F);
        if (writer) {
            float4* dst = (float4*)&slab[srow * SLABS + seg * 16];
            dst[0] = make_float4(cpP[0].x, cpP[0].y, cpP[1].x, cpP[1].y);
            dst[1] = make_float4(cpP[2].x, cpP[2].y, cpP[3].x, cpP[3].y);
            dst[2] = make_float4(cpP[4].x, cpP[4].y, cpP[5].x, cpP[5].y);
            dst[3] = make_float4(cpP[6].x, cpP[6].y, cpP[7].x, cpP[7].y);
            if (seg == 3) slab[srow * SLABS + 64] = c64;
        }
        __syncthreads();
        // v update: 8 lanes per column (4 slab reads each + 3-stage reduce)
        if (tid < 8 * KP1) {
            int col = tid >> 3, r8 = tid & 7;
            float cs = slab[r8 * SLABS + col]
                     + slab[(r8 + 8)  * SLABS + col]
                     + slab[(r8 + 16) * SLABS + col]
                     + slab[(r8 + 24) * SLABS + col];
            cs = DPP_ADD(cs, 0xB1);              // xor1
            cs = DPP_ADD(cs, 0x4E);              // xor2
            cs = SWZ_ADD(cs, 0x101F);            // xor4
            if (r8 == 0) {
                float nuj = (col == KK) ? nu_last : inv_n;
                vprev_sh[col] = v_sh[col];       // keep vt_{199} for final u
                v_sh[col] = nuj / cs;
            }
        }
        __syncthreads();
    }

    // ---- final pass A: ut per row (vs v_prev) -> stash in srt (sort buf dead) ----
    {
        float vp[16], vp64;
        #pragma unroll
        for (int j = 0; j < 16; j++) vp[j] = vprev_sh[seg * 16 + j];
        vp64 = vprev_sh[64];
        #pragma unroll
        for (int pr = 0; pr < NPAIRS; pr++) {
            const float4 pw = pairs_sh[pr * (NTEAMS * 4) + team * 4 + seg];
            int rowA = team + NTEAMS * (2 * pr);
            int rowB = rowA + NTEAMS;
            float hA = vp[0], hB = vp[0];
            #pragma unroll
            for (int m = 1; m < 16; m++) {
                hA = fmaf(hA, pw.y, vp[m]);
                hB = fmaf(hB, pw.w, vp[m]);
            }
            float pA = hA * pw.x, pB = hB * pw.z;
            if (seg == 3) { pA += vp64; pB += vp64; }
            pA = DPP_ADD(pA, 0xB1); pB = DPP_ADD(pB, 0xB1);
            pA = DPP_ADD(pA, 0x4E); pB = DPP_ADD(pB, 0x4E);
            if (seg == 0) {
                srt[rowA] = inv_n / pA;
                srt[rowB] = inv_n / pB;
            }
        }
    }
    __syncthreads();

    // ---- final pass B: outputs + norm (runs once) ----
    {
        float vloc[16], v64;
        #pragma unroll
        for (int j = 0; j < 16; j++) vloc[j] = v_sh[seg * 16 + j];
        v64 = v_sh[64];

        double npart = 0.0;
        #pragma unroll 1
        for (int r = 0; r < ROWS_PT; r++) {
            int row = team + NTEAMS * r;
            int pr = r >> 1, isB = r & 1;
            const float4 pw = pairs_sh[pr * (NTEAMS * 4) + team * 4 + seg];
            float wv  = isB ? pw.w : pw.y;
            float wcv = isB ? pw.z : pw.x;
            float si = ss[row];
            float u  = srt[row];
            // Gamma row segment: gm[m] = ut * w^(64-16s-m) * vt[m]
            float gm[16];
            float ug = u * wcv;
            #pragma unroll
            for (int m = 15; m >= 0; m--) { gm[m] = ug * vloc[m]; ug *= wv; }

            float g0sum = 0.0f;
            float* orow = out + ((size_t)b * NN + row) * KK + seg * 16;
            #pragma unroll
            for (int q = 0; q < 4; q++) {
                float4 o;
                #define DO_K(kk_, fld) { const int kl = 4 * q + kk_;            \
                    float dd = fabsf(topk_sh[seg * 16 + kl] - si);              \
                    float e  = __builtin_amdgcn_exp2f(dd * lt);                 \
                    float sg = 1.0f / (1.0f + e) + 1e-20f;                      \
                    float g0 = (sg * recS_sh[seg * 16 + kl]) * inv_n;           \
                    g0sum += g0;                                                \
                    float df = gm[kl] - g0; npart += (double)df * (double)df;   \
                    o.fld = gm[kl] * 2048.0f; }
                DO_K(0, x) DO_K(1, y) DO_K(2, z) DO_K(3, w)
                #undef DO_K
                ((float4*)orow)[q] = o;
            }
            float gtot = g0sum;
            gtot = DPP_ADD(gtot, 0xB1);
            gtot = DPP_ADD(gtot, 0x4E);
            if (seg == 3) {
                float last = inv_n - gtot;
                last = fminf(fmaxf(last, 1e-20f), 1.0f - 1e-20f);   // clip
                float gm64 = u * v64;            // M_{i,64} = w^0 = 1
                float df = gm64 - last;
                npart += (double)df * (double)df;
            }
        }

        __syncthreads();
        red_sh[tid] = npart;
        __syncthreads();
        for (int s2 = NTHREADS / 2; s2 > 0; s2 >>= 1) {
            if (tid < s2) red_sh[tid] += red_sh[tid + s2];
            __syncthreads();
        }
        if (tid == 0) atomicAdd(norm_acc, red_sh[0]);
    }
}

// ---- kernel 3: finalize norm ----
__global__ void finalize_kernel(const double* __restrict__ norm_acc, float* __restrict__ out) {
    if (threadIdx.x == 0 && blockIdx.x == 0)
        out[(size_t)BS * NN * KK] = (float)sqrt(*norm_acc);
}

extern "C" void kernel_launch(void* const* d_in, const int* in_sizes, int n_in,
                              void* d_out, int out_size, void* d_ws, size_t ws_size,
                              hipStream_t stream) {
    const float* scores = (const float*)d_in[0];
    const float* W = (const float*)d_in[1];
    float* out = (float*)d_out;

    // ws layout: [0..3] max_enc(0), [4..7] inf_count(0),
    //            [8..15] norm_acc double(0), [16..19] min_enc(0xFFFFFFFF)
    unsigned* maxenc = (unsigned*)d_ws;
    unsigned* infc   = maxenc + 1;
    double*  nacc    = (double*)((char*)d_ws + 8);
    unsigned* minenc = (unsigned*)((char*)d_ws + 16);

    hipMemsetAsync(d_ws, 0, 16, stream);
    hipMemsetAsync((char*)d_ws + 16, 0xFF, 4, stream);

    hipLaunchKernelGGL(minmax_kernel, dim3(256), dim3(256), 0, stream,
                       scores, maxenc, minenc, infc);
    hipLaunchKernelGGL(sink_main, dim3(BS), dim3(NTHREADS), 0, stream,
                       scores, W, out, maxenc, minenc, infc, nacc);
    hipLaunchKernelGGL(finalize_kernel, dim3(1), dim3(64), 0, stream, nacc, out);
}

// Round 10
// 785.400 us; speedup vs baseline: 6.3305x; 1.0085x over previous
//
#include <hip/hip_runtime.h>
#include <math.h>

#define BS 256
#define NN 2048
#define KK 64
#define KP1 65
#define NTHREADS 1024
#define NTEAMS 256           // NTHREADS/4 teams; 4 lanes per team
#define ROWS_PT 8            // NN / NTEAMS rows per team
#define NPAIRS 4             // ROWS_PT/2 row-pairs per team
#define MAX_ITER 200
#define SLABR 64             // one slab row per 16-lane group (4 per wave)
#define SLABS 68             // slab row stride (floats): 16B-aligned rows

// cross-lane helpers. ROUND-10: the reduce tree uses ONLY DPP row ops
// (row_ror:4 = 0x124, row_ror:8 = 0x128 — x += ror4(x); x += ror8(x) sums
// the coset {l, l+4, l+8, l+12} within a 16-lane row, which is exactly what
// the writer lanes 0-3 need).  This removes the 32 ds_swizzle/lane/iter that
// kept the DS pipe ~60% busy on the serial critical path (rounds 5-9:
// SQ_LDS_BANK_CONFLICT pinned at 7.63M).  quad_perm xor1=0xB1, xor2=0x4E
// stay for the 4-lane row-sum reduce; ds_swizzle xor4=0x101F survives only
// in the 520-thread tail.
#define DPP_ADD(x, ctrl) ((x) + __int_as_float(__builtin_amdgcn_mov_dpp(      \
                              __float_as_int(x), (ctrl), 0xF, 0xF, true)))
#define SWZ_ADD(x, pat)  ((x) + __int_as_float(__builtin_amdgcn_ds_swizzle(   \
                              __float_as_int(x), (pat))))
#define DPPF(x, ctrl) __int_as_float(__builtin_amdgcn_mov_dpp(                \
                              __float_as_int(x), (ctrl), 0xF, 0xF, true))

// packed fp32: native <2 x float> ops (round 9) — LLVM selects
// v_pk_{fma,add,mul}_f32 with full regalloc freedom.
typedef float f2 __attribute__((ext_vector_type(2)));

#if __has_builtin(__builtin_elementwise_fma)
__device__ __forceinline__ f2 pkfma(f2 a, f2 b, f2 c) {
    return __builtin_elementwise_fma(a, b, c);
}
#else
__device__ __forceinline__ f2 pkfma(f2 a, f2 b, f2 c) {
    f2 d;
    asm("v_pk_fma_f32 %0, %1, %2, %3" : "=v"(d) : "v"(a), "v"(b), "v"(c));
    return d;
}
#endif
__device__ __forceinline__ f2 splat2(float b) { f2 s; s.x = b; s.y = b; return s; }

// broadcast lane p of each 4-lane quad (compile-time p via switch)
__device__ __forceinline__ float quad_bcast(float v, int pr) {
    int i = __float_as_int(v), r;
    switch (pr & 3) {
        case 0:  r = __builtin_amdgcn_mov_dpp(i, 0x00, 0xF, 0xF, true); break;
        case 1:  r = __builtin_amdgcn_mov_dpp(i, 0x55, 0xF, 0xF, true); break;
        case 2:  r = __builtin_amdgcn_mov_dpp(i, 0xAA, 0xF, 0xF, true); break;
        default: r = __builtin_amdgcn_mov_dpp(i, 0xFF, 0xF, 0xF, true); break;
    }
    return __int_as_float(r);
}

// 2-stage DPP cross-team reduce within each 16-lane row (ror4 + ror8):
// writer lanes 0-3 end with the sum over the 4 teams of their row.
__device__ __forceinline__ f2 row_reduce(f2 v) {
    f2 t;
    t.x = DPPF(v.x, 0x124); t.y = DPPF(v.y, 0x124); v = v + t;   // ror:4
    t.x = DPPF(v.x, 0x128); t.y = DPPF(v.y, 0x128); v = v + t;   // ror:8
    return v;
}

// ---- monotone float<->uint encoding for atomic min/max ----
__device__ __forceinline__ unsigned enc_f32(float f) {
    unsigned b = __float_as_uint(f);
    return b ^ (unsigned)(((int)b >> 31) | (int)0x80000000);
}
__device__ __forceinline__ float dec_f32(unsigned e) {
    unsigned b = (e & 0x80000000u) ? (e & 0x7FFFFFFFu) : ~e;
    return __uint_as_float(b);
}

// ---- kernel 1: global min/max of scores (ignoring -inf for min), count -inf ----
__global__ void minmax_kernel(const float* __restrict__ s,
                              unsigned* __restrict__ maxenc,
                              unsigned* __restrict__ minenc,
                              unsigned* __restrict__ infc) {
    int tid = blockIdx.x * blockDim.x + threadIdx.x;
    int stride = gridDim.x * blockDim.x;
    float mx = -INFINITY, mn = INFINITY;
    unsigned cnt = 0;
    for (int i = tid; i < BS * NN; i += stride) {
        float v = s[i];
        if (isinf(v) && v < 0.0f) cnt++;
        else { mx = fmaxf(mx, v); mn = fminf(mn, v); }
    }
    for (int off = 32; off > 0; off >>= 1) {
        mx = fmaxf(mx, __shfl_down(mx, off));
        mn = fminf(mn, __shfl_down(mn, off));
        cnt += __shfl_down(cnt, off);
    }
    __shared__ float smx[8], smn[8];
    __shared__ unsigned scnt[8];
    int wid = threadIdx.x >> 6, lane = threadIdx.x & 63;
    if (lane == 0) { smx[wid] = mx; smn[wid] = mn; scnt[wid] = cnt; }
    __syncthreads();
    if (threadIdx.x == 0) {
        int nw = blockDim.x >> 6;
        for (int w = 1; w < nw; w++) { mx = fmaxf(mx, smx[w]); mn = fminf(mn, smn[w]); cnt += scnt[w]; }
        atomicMax(maxenc, enc_f32(mx));
        atomicMin(minenc, enc_f32(mn));
        if (cnt) atomicAdd(infc, cnt);
    }
}

// ---- kernel 2: per-batch sort + tau + Gamma0 + 200-iter Sinkhorn + outputs ----
// Factorization: Sinkhorn on M_ij = w_i^(64-j), w_i = exp2(-2*negc2*s_i), with
// vt0 = q/65 is exactly equivalent to the reference (ut=u*p, vt=q*v).
// Structure: DPP-only cross-team reduce (ror4+ror8) -> per-16-lane-row slab
// rows (64), packed-f32 Horner row pass + packed geometric col chain, 2
// lane-distributed IEEE divides/thread, parallel 520-thread v-update tail.
// amdgpu_waves_per_eu(4,4): with 106KB LDS only 1 block/CU fits (16 waves =
// 4/EU), so this legalizes the full 128-VGPR budget at zero occupancy cost
// (launch_bounds' 2nd arg was proven inert in round 2).
__global__ void __launch_bounds__(NTHREADS)
__attribute__((amdgpu_waves_per_eu(4, 4)))
sink_main(const float* __restrict__ scores, const float* __restrict__ W,
          float* __restrict__ out,
          const unsigned* __restrict__ maxenc, const unsigned* __restrict__ minenc,
          const unsigned* __restrict__ infc, double* __restrict__ norm_acc)
{
    const int tid  = threadIdx.x;
    const int b    = blockIdx.x;
    const int team = tid >> 2;     // 0..255
    const int seg  = tid & 3;      // 0..3
    const int wid  = tid >> 6;     // wave id 0..15
    const int lane = tid & 63;

    __shared__ float ss[NN];                                   // filled scores
    __shared__ float srt[NN];                                  // sort buf; later ut per row
    __shared__ float4 pairs_sh[NPAIRS * NTEAMS * 4];           // (wcA,wA,wcB,wB) per (pr,team,seg)
    __shared__ float v_sh[68] __attribute__((aligned(16)));    // vt (65 used)
    __shared__ float vprev_sh[68];                             // vt_{t-1}
    __shared__ float slab[SLABR * SLABS] __attribute__((aligned(16))); // per-16-lane-row partials
    __shared__ double red_sh[NTHREADS];
    __shared__ float recS_sh[KK];
    __shared__ float topk_sh[KK];

    const float LOG2E   = 1.4426950408889634f;
    const float inv_n   = 1.0f / 2048.0f;        // exact
    const float nu_last = 1984.0f / 2048.0f;     // exact

    // global scalars
    float smax = dec_f32(*maxenc);
    float smin = dec_f32(*minenc);
    unsigned icnt = *infc;
    float filled = smin - (smax - smin);
    float slo = (icnt > 0) ? filled : smin;
    // C.max() attained at an extreme s with anchor 0 or 64 (convexity)
    float cA = slo * slo, cB = (slo - 64.0f) * (slo - 64.0f);
    float cC = smax * smax, cD = (smax - 64.0f) * (smax - 64.0f);
    float Cmax = fmaxf(fmaxf(cA, cB), fmaxf(cC, cD));
    float negc2 = -(10.0f * LOG2E) / Cmax;       // exp(-C/Cmax/0.1) == exp2(d*d*negc2)
    float m2 = -2.0f * negc2;                    // w = exp2(m2 * s)

    // load + -inf fill
    for (int i = tid; i < NN; i += NTHREADS) {
        float v = scores[(size_t)b * NN + i];
        if (isinf(v) && v < 0.0f) v = filled;
        ss[i] = v; srt[i] = v;
    }
    __syncthreads();

    // bitonic sort (ascending); 1 pair per thread per substep
    for (int size = 2; size <= NN; size <<= 1) {
        for (int stride = size >> 1; stride > 0; stride >>= 1) {
            #pragma unroll
            for (int pp = 0; pp < (NN / 2) / NTHREADS; pp++) {
                int p = tid + pp * NTHREADS;
                int lo = ((p & ~(stride - 1)) << 1) | (p & (stride - 1));
                int hi = lo + stride;
                bool up = ((lo & size) == 0);
                float x = srt[lo], y = srt[hi];
                if ((x > y) == up) { srt[lo] = y; srt[hi] = x; }
            }
            __syncthreads();
        }
    }

    // topk (descending) from sorted
    for (int k = tid; k < KK; k += NTHREADS) topk_sh[k] = srt[NN - 1 - k];

    // tau = sum(sorted * W), fp64 accumulate
    double tp = 0.0;
    for (int i = tid; i < NN; i += NTHREADS) tp += (double)srt[i] * (double)W[i];
    red_sh[tid] = tp;
    __syncthreads();
    for (int s2 = NTHREADS / 2; s2 > 0; s2 >>= 1) {
        if (tid < s2) red_sh[tid] += red_sh[tid + s2];
        __syncthreads();
    }
    float tau = (float)red_sh[0];
    float lt = LOG2E / tau;                      // sigma = 1/(1+exp2(|d|*lt))

    // init vt0 = q/65 (q_j = exp2(negc2*(64-j)^2))
    if (tid < KP1) {
        float a = (float)(KK - tid);
        v_sh[tid] = __builtin_amdgcn_exp2f(negc2 * a * a) * (1.0f / 65.0f);
    }

    // pairs table: (wcA, wA, wcB, wB) per (pr, team, seg); wc = w^(49-16*seg)
    for (int item = tid; item < NPAIRS * NTEAMS * 4; item += NTHREADS) {
        int pr = item >> 10;                 // NTEAMS*4 = 1024
        int tm = (item >> 2) & (NTEAMS - 1);
        int sg = item & 3;
        int rowA = tm + NTEAMS * (2 * pr);
        int rowB = rowA + NTEAMS;
        float wA = __builtin_amdgcn_exp2f(m2 * ss[rowA]);
        float wB = __builtin_amdgcn_exp2f(m2 * ss[rowB]);
        float a2 = wA * wA, a4 = a2 * a2, a8 = a4 * a4, a16 = a8 * a8;
        float b2 = wB * wB, b4 = b2 * b2, b8 = b4 * b4, b16 = b8 * b8;
        float wcA = wA, wcB = wB;            // sg==3: w^1
        if (sg < 3) { wcA *= a16; wcB *= b16; }   // sg==2: w^17
        if (sg < 2) { wcA *= a16; wcB *= b16; }   // sg==1: w^33
        if (sg < 1) { wcA *= a16; wcB *= b16; }   // sg==0: w^49
        pairs_sh[item] = make_float4(wcA, wA, wcB, wB);
    }
    __syncthreads();

    const bool writer = ((lane & 12) == 0);      // lanes 0-3 of each 16-lane row
    const int  srow   = wid * 4 + (lane >> 4);   // this 16-lane row's slab row

    // ---- Gamma0 column sums S_k: DPP row-reduce + per-row slab write ----
    {
        float tk[16];
        #pragma unroll
        for (int kk = 0; kk < 16; kk++) tk[kk] = topk_sh[seg * 16 + kk];
        float part[16];
        #pragma unroll
        for (int kk = 0; kk < 16; kk++) part[kk] = 0.0f;
        #pragma unroll 1
        for (int r = 0; r < ROWS_PT; r++) {
            float si = ss[team + NTEAMS * r];
            #pragma unroll
            for (int kk = 0; kk < 16; kk++) {
                float d = fabsf(tk[kk] - si);
                float e = __builtin_amdgcn_exp2f(d * lt);
                part[kk] += 1.0f / (1.0f + e) + 1e-20f;
            }
        }
        #pragma unroll
        for (int kk = 0; kk < 16; kk++) {
            part[kk] = DPP_ADD(part[kk], 0x124);    // ror:4
            part[kk] = DPP_ADD(part[kk], 0x128);    // ror:8
        }
        if (writer) {
            float4* dst = (float4*)&slab[srow * SLABS + seg * 16];
            dst[0] = make_float4(part[0], part[1], part[2], part[3]);
            dst[1] = make_float4(part[4], part[5], part[6], part[7]);
            dst[2] = make_float4(part[8], part[9], part[10], part[11]);
            dst[3] = make_float4(part[12], part[13], part[14], part[15]);
        }
    }
    __syncthreads();
    if (tid < KK) {
        float sum = 0.0f;
        #pragma unroll
        for (int g = 0; g < SLABR; g++) sum += slab[g * SLABS + tid];
        recS_sh[tid] = 1.0f / sum;
    }
    __syncthreads();

    // ---- Sinkhorn: 200 iterations; two-phase (rows then cols) ----
    for (int t = 0; t < MAX_ITER; t++) {
        f2 vl2[8] __attribute__((aligned(16)));   // {v[2q], v[2q+1]} pairs
        #pragma unroll
        for (int q = 0; q < 4; q++)
            ((float4*)vl2)[q] = ((const float4*)(v_sh + seg * 16))[q];
        const float v64 = v_sh[64];
        const f2 v64p = splat2(v64);

        // phase 1: row sums (Horner) for all 4 pairs; lane keeps pair==seg
        f2 myP = splat2(1.0f);
        #pragma unroll
        for (int pr = 0; pr < NPAIRS; pr++) {
            const float4 pw = pairs_sh[pr * (NTEAMS * 4) + team * 4 + seg];
            const f2 wA2p = splat2(pw.y * pw.y);
            const f2 wB2p = splat2(pw.w * pw.w);
            f2 hA2 = vl2[0], hB2 = vl2[0];
            #pragma unroll
            for (int q = 1; q < 8; q++) {
                hA2 = pkfma(hA2, wA2p, vl2[q]);   // h = h*w^2 + v[q]
                hB2 = pkfma(hB2, wB2p, vl2[q]);
            }
            f2 pP;
            pP.x = fmaf(hA2.x, pw.y, hA2.y) * pw.x;
            pP.y = fmaf(hB2.x, pw.w, hB2.y) * pw.z;
            if (seg == 3) pP = pP + v64p;         // j=64 term, M=1
            f2 tq;
            tq.x = DPPF(pP.x, 0xB1); tq.y = DPPF(pP.y, 0xB1); // xor1
            pP = pP + tq;
            tq.x = DPPF(pP.x, 0x4E); tq.y = DPPF(pP.y, 0x4E); // xor2
            pP = pP + tq;
            myP.x = (seg == pr) ? pP.x : myP.x;   // keep my pair's sums
            myP.y = (seg == pr) ? pP.y : myP.y;
        }
        const float uAm = inv_n / myP.x;          // 2 IEEE divs, lane-distributed
        const float uBm = inv_n / myP.y;

        // phase 2: col sums (geometric chain), u re-broadcast per pair
        f2 cpP[8];
        float c64 = 0.0f;
        #pragma unroll
        for (int pr = 0; pr < NPAIRS; pr++) {
            const float uA = quad_bcast(uAm, pr);
            const float uB = quad_bcast(uBm, pr);
            const float4 pw = pairs_sh[pr * (NTEAMS * 4) + team * 4 + seg];
            const f2 wA2p = splat2(pw.y * pw.y);
            const f2 wB2p = splat2(pw.w * pw.w);
            float tclA = uA * pw.x, tclB = uB * pw.z;
            f2 tA, tB;
            tA.x = tclA * pw.y; tA.y = tclA;      // cols {2p, 2p+1} at p=7
            tB.x = tclB * pw.w; tB.y = tclB;
            if (pr == 0) {
                #pragma unroll
                for (int p = 7; p >= 0; p--) {
                    cpP[p] = tA + tB;             // == (0+tA)+tB bit-exact
                    if (p) { tA = tA * wA2p; tB = tB * wB2p; }
                }
            } else {
                #pragma unroll
                for (int p = 7; p >= 0; p--) {
                    cpP[p] = (cpP[p] + tA) + tB;
                    if (p) { tA = tA * wA2p; tB = tB * wB2p; }
                }
            }
            if (seg == 3) c64 += uA + uB;         // col j=64: M=1
        }

        // cross-team reduce within each 16-lane row (pure DPP)
        #pragma unroll
        for (int p = 0; p < 8; p++) cpP[p] = row_reduce(cpP[p]);
        c64 = DPP_ADD(c64, 0x124);
        c64 = DPP_ADD(c64, 0x128);
        if (writer) {
            float4* dst = (float4*)&slab[srow * SLABS + seg * 16];
            dst[0] = make_float4(cpP[0].x, cpP[0].y, cpP[1].x, cpP[1].y);
            dst[1] = make_float4(cpP[2].x, cpP[2].y, cpP[3].x, cpP[3].y);
            dst[2] = make_float4(cpP[4].x, cpP[4].y, cpP[5].x, cpP[5].y);
            dst[3] = make_float4(cpP[6].x, cpP[6].y, cpP[7].x, cpP[7].y);
            if (seg == 3) slab[srow * SLABS + 64] = c64;
        }
        __syncthreads();
        // v update: 8 lanes per column (8 slab reads each + 3-stage reduce)
        if (tid < 8 * KP1) {
            int col = tid >> 3, r8 = tid & 7;
            float cs = 0.0f;
            #pragma unroll
            for (int k = 0; k < 8; k++) cs += slab[(r8 + 8 * k) * SLABS + col];
            cs = DPP_ADD(cs, 0xB1);              // xor1
            cs = DPP_ADD(cs, 0x4E);              // xor2
            cs = SWZ_ADD(cs, 0x101F);            // xor4
            if (r8 == 0) {
                float nuj = (col == KK) ? nu_last : inv_n;
                vprev_sh[col] = v_sh[col];       // keep vt_{199} for final u
                v_sh[col] = nuj / cs;
            }
        }
        __syncthreads();
    }

    // ---- final pass A: ut per row (vs v_prev) -> stash in srt (sort buf dead) ----
    {
        float vp[16], vp64;
        #pragma unroll
        for (int j = 0; j < 16; j++) vp[j] = vprev_sh[seg * 16 + j];
        vp64 = vprev_sh[64];
        #pragma unroll
        for (int pr = 0; pr < NPAIRS; pr++) {
            const float4 pw = pairs_sh[pr * (NTEAMS * 4) + team * 4 + seg];
            int rowA = team + NTEAMS * (2 * pr);
            int rowB = rowA + NTEAMS;
            float hA = vp[0], hB = vp[0];
            #pragma unroll
            for (int m = 1; m < 16; m++) {
                hA = fmaf(hA, pw.y, vp[m]);
                hB = fmaf(hB, pw.w, vp[m]);
            }
            float pA = hA * pw.x, pB = hB * pw.z;
            if (seg == 3) { pA += vp64; pB += vp64; }
            pA = DPP_ADD(pA, 0xB1); pB = DPP_ADD(pB, 0xB1);
            pA = DPP_ADD(pA, 0x4E); pB = DPP_ADD(pB, 0x4E);
            if (seg == 0) {
                srt[rowA] = inv_n / pA;
                srt[rowB] = inv_n / pB;
            }
        }
    }
    __syncthreads();

    // ---- final pass B: outputs + norm (runs once) ----
    {
        float vloc[16], v64;
        #pragma unroll
        for (int j = 0; j < 16; j++) vloc[j] = v_sh[seg * 16 + j];
        v64 = v_sh[64];

        double npart = 0.0;
        #pragma unroll 1
        for (int r = 0; r < ROWS_PT; r++) {
            int row = team + NTEAMS * r;
            int pr = r >> 1, isB = r & 1;
            const float4 pw = pairs_sh[pr * (NTEAMS * 4) + team * 4 + seg];
            float wv  = isB ? pw.w : pw.y;
            float wcv = isB ? pw.z : pw.x;
            float si = ss[row];
            float u  = srt[row];
            // Gamma row segment: gm[m] = ut * w^(64-16s-m) * vt[m]
            float gm[16];
            float ug = u * wcv;
            #pragma unroll
            for (int m = 15; m >= 0; m--) { gm[m] = ug * vloc[m]; ug *= wv; }

            float g0sum = 0.0f;
            float* orow = out + ((size_t)b * NN + row) * KK + seg * 16;
            #pragma unroll
            for (int q = 0; q < 4; q++) {
                float4 o;
                #define DO_K(kk_, fld) { const int kl = 4 * q + kk_;            \
                    float dd = fabsf(topk_sh[seg * 16 + kl] - si);              \
                    float e  = __builtin_amdgcn_exp2f(dd * lt);                 \
                    float sg = 1.0f / (1.0f + e) + 1e-20f;                      \
                    float g0 = (sg * recS_sh[seg * 16 + kl]) * inv_n;           \
                    g0sum += g0;                                                \
                    float df = gm[kl] - g0; npart += (double)df * (double)df;   \
                    o.fld = gm[kl] * 2048.0f; }
                DO_K(0, x) DO_K(1, y) DO_K(2, z) DO_K(3, w)
                #undef DO_K
                ((float4*)orow)[q] = o;
            }
            float gtot = g0sum;
            gtot = DPP_ADD(gtot, 0xB1);
            gtot = DPP_ADD(gtot, 0x4E);
            if (seg == 3) {
                float last = inv_n - gtot;
                last = fminf(fmaxf(last, 1e-20f), 1.0f - 1e-20f);   // clip
                float gm64 = u * v64;            // M_{i,64} = w^0 = 1
                float df = gm64 - last;
                npart += (double)df * (double)df;
            }
        }

        __syncthreads();
        red_sh[tid] = npart;
        __syncthreads();
        for (int s2 = NTHREADS / 2; s2 > 0; s2 >>= 1) {
            if (tid < s2) red_sh[tid] += red_sh[tid + s2];
            __syncthreads();
        }
        if (tid == 0) atomicAdd(norm_acc, red_sh[0]);
    }
}

// ---- kernel 3: finalize norm ----
__global__ void finalize_kernel(const double* __restrict__ norm_acc, float* __restrict__ out) {
    if (threadIdx.x == 0 && blockIdx.x == 0)
        out[(size_t)BS * NN * KK] = (float)sqrt(*norm_acc);
}

extern "C" void kernel_launch(void* const* d_in, const int* in_sizes, int n_in,
                              void* d_out, int out_size, void* d_ws, size_t ws_size,
                              hipStream_t stream) {
    const float* scores = (const float*)d_in[0];
    const float* W = (const float*)d_in[1];
    float* out = (float*)d_out;

    // ws layout: [0..3] max_enc(0), [4..7] inf_count(0),
    //            [8..15] norm_acc double(0), [16..19] min_enc(0xFFFFFFFF)
    unsigned* maxenc = (unsigned*)d_ws;
    unsigned* infc   = maxenc + 1;
    double*  nacc    = (double*)((char*)d_ws + 8);
    unsigned* minenc = (unsigned*)((char*)d_ws + 16);

    hipMemsetAsync(d_ws, 0, 16, stream);
    hipMemsetAsync((char*)d_ws + 16, 0xFF, 4, stream);

    hipLaunchKernelGGL(minmax_kernel, dim3(256), dim3(256), 0, stream,
                       scores, maxenc, minenc, infc);
    hipLaunchKernelGGL(sink_main, dim3(BS), dim3(NTHREADS), 0, stream,
                       scores, W, out, maxenc, minenc, infc, nacc);
    hipLaunchKernelGGL(finalize_kernel, dim3(1), dim3(64), 0, stream, nacc, out);
}